// Round 1
// baseline (1832.735 us; speedup 1.0000x reference)
//
#include <hip/hip_runtime.h>
#include <hip/hip_bf16.h>
#include <math.h>

#define NN 50000
#define NE 1600000
#define D 128
#define NRBF 50
#define RCUT 5.0f
#define LNEPS 1e-5f
#define EB 16           // edges per batch in edge kernels
#define EDGE_GRID 2048  // grid-stride blocks for edge kernels

__device__ __forceinline__ float silu_f(float x) {
    return x / (1.0f + __expf(-x));
}

// ---------------------------------------------------------------- kernel 1
// nbr = silu(z @ A_nbr_w + A_nbr_b)   (one node per 128-thread block)
__global__ __launch_bounds__(128) void nbr_kernel(
    const float* __restrict__ z, const float* __restrict__ Aw,
    const float* __restrict__ Ab, float* __restrict__ nbr)
{
    const int n = blockIdx.x;
    const int d = threadIdx.x;
    float acc = Ab[d];
#pragma unroll
    for (int k = 0; k < 25; ++k)
        acc = fmaf(z[n * 25 + k], Aw[k * D + d], acc);
    nbr[(size_t)n * D + d] = silu_f(acc);
}

// ---------------------------------------------------------------- kernel 2
// per-edge: rbf, c, gate = (rbf@W_ndp+b)*c, msg = nbr[j]*gate, atomic m[i] +=
// also writes rt0, rt1, rt2, c outputs.
__global__ __launch_bounds__(256) void edge_msg_kernel(
    const int* __restrict__ edge, const float* __restrict__ r,
    const float* __restrict__ u, const float* __restrict__ W_ndp,
    const float* __restrict__ b_ndp, const float* __restrict__ nbr,
    float* __restrict__ m, float* __restrict__ rt0, float* __restrict__ rt1,
    float* __restrict__ rt2, float* __restrict__ cout)
{
    __shared__ float rbf_s[EB][52];   // row = 208B, 16B-aligned
    __shared__ float er_s[EB];
    __shared__ float c_s[EB];

    const int tid  = threadIdx.x;
    const int d    = tid & 127;
    const int half = tid >> 7;

    // W_ndp column d in registers (loaded once per block)
    float wreg[NRBF];
#pragma unroll
    for (int k = 0; k < NRBF; ++k) wreg[k] = W_ndp[k * D + d];
    const float bd = b_ndp[d];

    const float start = expf(-RCUT);                 // const-folded
    const float step  = (1.0f - start) / (NRBF - 1);
    const float bq    = (2.0f / NRBF) * (1.0f - start);
    const float beta  = 1.0f / (bq * bq);

    const int nbatch = NE / EB;
    for (int batch = blockIdx.x; batch < nbatch; batch += gridDim.x) {
        const int eb = batch * EB;
        // ---- phase A: per-edge scalars + rt outputs
        if (tid < EB) {
            const int e = eb + tid;
            const float rr = r[e];
            er_s[tid] = __expf(-rr);
            const float cc = (rr < RCUT)
                ? 0.5f * (__cosf(3.14159265358979f * rr * (1.0f / RCUT)) + 1.0f)
                : 0.0f;
            c_s[tid] = cc;
            rt0[e] = rr;
            cout[e] = cc;
        } else if (tid >= 64 && tid < 64 + EB * 8) {
            const int idx  = tid - 64;
            const int el   = idx >> 3;
            const int comp = idx & 7;
            const int e    = eb + el;
            const float x = u[e * 3 + 0];
            const float y = u[e * 3 + 1];
            const float zc = u[e * 3 + 2];
            const float s3 = 1.7320508075688772f;
            if (comp < 3) {
                rt1[(size_t)e * 3 + comp] = (comp == 0) ? x : (comp == 1 ? y : zc);
            } else {
                float v;
                switch (comp) {
                    case 3: v = s3 * x * y; break;
                    case 4: v = s3 * y * zc; break;
                    case 5: v = 0.5f * (3.0f * zc * zc - 1.0f); break;
                    case 6: v = s3 * zc * x; break;
                    default: v = 0.5f * s3 * (x * x - y * y); break;
                }
                rt2[(size_t)e * 5 + (comp - 3)] = v;
            }
        }
        __syncthreads();
        // ---- phase B: rbf fill (16 edges x 50)
        for (int idx = tid; idx < EB * 64; idx += 256) {
            const int el = idx >> 6;
            const int k  = idx & 63;
            if (k < NRBF) {
                const float diff = er_s[el] - (start + (float)k * step);
                rbf_s[el][k] = __expf(-beta * diff * diff);
            }
        }
        __syncthreads();
        // ---- phase C: gate, msg, atomic scatter (each half does 8 edges)
        for (int s = 0; s < 8; ++s) {
            const int el = half * 8 + s;
            const int e  = eb + el;
            const int vi = edge[2 * e];
            const int vj = edge[2 * e + 1];
            float acc = bd;
#pragma unroll
            for (int k = 0; k < NRBF; ++k)
                acc = fmaf(rbf_s[el][k], wreg[k], acc);
            const float gate = acc * c_s[el];
            const float msgv = nbr[(size_t)vj * D + d] * gate;
            unsafeAtomicAdd(&m[(size_t)vi * D + d], msgv);
        }
        __syncthreads();
    }
}

// ---------------------------------------------------------------- kernel 3
// na = silu(z@A_na+b); h1 = [na,m]@W_nrd+b; LN; silu; h = h1@W_nru+b
__global__ __launch_bounds__(128) void node_kernel(
    const float* __restrict__ z, const float* __restrict__ A_na_w,
    const float* __restrict__ A_na_b, const float* __restrict__ m,
    const float* __restrict__ W_nrd_w, const float* __restrict__ W_nrd_b,
    const float* __restrict__ W_nru_w, const float* __restrict__ W_nru_b,
    const float* __restrict__ ln_g, const float* __restrict__ ln_b,
    float* __restrict__ hout)
{
    __shared__ float buf[256];
    __shared__ float red[4];
    const int n = blockIdx.x;
    const int d = threadIdx.x;

    float acc = A_na_b[d];
#pragma unroll
    for (int k = 0; k < 25; ++k)
        acc = fmaf(z[n * 25 + k], A_na_w[k * D + d], acc);
    buf[d]       = silu_f(acc);
    buf[128 + d] = m[(size_t)n * D + d];
    __syncthreads();

    float h1 = W_nrd_b[d];
#pragma unroll 8
    for (int k = 0; k < 256; ++k)
        h1 = fmaf(buf[k], W_nrd_w[k * D + d], h1);

    // LayerNorm stats across 128 threads (2 waves)
    float s = h1, sq = h1 * h1;
#pragma unroll
    for (int off = 32; off >= 1; off >>= 1) {
        s  += __shfl_xor(s, off);
        sq += __shfl_xor(sq, off);
    }
    const int wv = d >> 6;
    if ((d & 63) == 0) { red[wv] = s; red[2 + wv] = sq; }
    __syncthreads();
    const float tot   = red[0] + red[1];
    const float totsq = red[2] + red[3];
    const float mu  = tot * (1.0f / 128.0f);
    const float var = totsq * (1.0f / 128.0f) - mu * mu;
    const float inv = rsqrtf(var + LNEPS);
    float y = (h1 - mu) * inv * ln_g[d] + ln_b[d];
    y = silu_f(y);
    __syncthreads();       // all reads of buf done (guaranteed by red barrier)
    buf[d] = y;
    __syncthreads();

    float h2 = W_nru_b[d];
#pragma unroll 8
    for (int k = 0; k < 128; ++k)
        h2 = fmaf(buf[k], W_nru_w[k * D + d], h2);
    hout[(size_t)n * D + d] = h2;
}

// ---------------------------------------------------------------- kernel 4
// t = (h[i]+h[j]) * (rbf @ W_erp + b)
__global__ __launch_bounds__(256) void edge_out_kernel(
    const int* __restrict__ edge, const float* __restrict__ r,
    const float* __restrict__ W_erp, const float* __restrict__ b_erp,
    const float* __restrict__ h, float* __restrict__ t)
{
    __shared__ float rbf_s[EB][52];
    __shared__ float er_s[EB];

    const int tid  = threadIdx.x;
    const int d    = tid & 127;
    const int half = tid >> 7;

    float wreg[NRBF];
#pragma unroll
    for (int k = 0; k < NRBF; ++k) wreg[k] = W_erp[k * D + d];
    const float bd = b_erp[d];

    const float start = expf(-RCUT);
    const float step  = (1.0f - start) / (NRBF - 1);
    const float bq    = (2.0f / NRBF) * (1.0f - start);
    const float beta  = 1.0f / (bq * bq);

    const int nbatch = NE / EB;
    for (int batch = blockIdx.x; batch < nbatch; batch += gridDim.x) {
        const int eb = batch * EB;
        if (tid < EB) {
            er_s[tid] = __expf(-r[eb + tid]);
        }
        __syncthreads();
        for (int idx = tid; idx < EB * 64; idx += 256) {
            const int el = idx >> 6;
            const int k  = idx & 63;
            if (k < NRBF) {
                const float diff = er_s[el] - (start + (float)k * step);
                rbf_s[el][k] = __expf(-beta * diff * diff);
            }
        }
        __syncthreads();
        for (int s = 0; s < 8; ++s) {
            const int el = half * 8 + s;
            const int e  = eb + el;
            const int vi = edge[2 * e];
            const int vj = edge[2 * e + 1];
            float acc = bd;
#pragma unroll
            for (int k = 0; k < NRBF; ++k)
                acc = fmaf(rbf_s[el][k], wreg[k], acc);
            const float tv = (h[(size_t)vi * D + d] + h[(size_t)vj * D + d]) * acc;
            t[(size_t)e * D + d] = tv;
        }
        __syncthreads();
    }
}

// ---------------------------------------------------------------- launch
extern "C" void kernel_launch(void* const* d_in, const int* in_sizes, int n_in,
                              void* d_out, int out_size, void* d_ws, size_t ws_size,
                              hipStream_t stream) {
    const float* z      = (const float*)d_in[0];
    const int*   edge   = (const int*)d_in[1];
    const float* r      = (const float*)d_in[2];
    const float* u      = (const float*)d_in[3];
    const float* A_na_w  = (const float*)d_in[4];
    const float* A_na_b  = (const float*)d_in[5];
    const float* A_nbr_w = (const float*)d_in[6];
    const float* A_nbr_b = (const float*)d_in[7];
    const float* W_ndp_w = (const float*)d_in[8];
    const float* W_ndp_b = (const float*)d_in[9];
    const float* W_nrd_w = (const float*)d_in[10];
    const float* W_nrd_b = (const float*)d_in[11];
    const float* W_nru_w = (const float*)d_in[12];
    const float* W_nru_b = (const float*)d_in[13];
    const float* W_erp_w = (const float*)d_in[14];
    const float* W_erp_b = (const float*)d_in[15];
    const float* ln_g    = (const float*)d_in[16];
    const float* ln_b    = (const float*)d_in[17];

    float* out = (float*)d_out;
    // output layout (flat, fp32): h | t | rt0 | rt1 | rt2 | c
    float* h_out   = out;
    float* t_out   = out + (size_t)NN * D;
    float* rt0_out = t_out + (size_t)NE * D;
    float* rt1_out = rt0_out + (size_t)NE;
    float* rt2_out = rt1_out + (size_t)NE * 3;
    float* c_out   = rt2_out + (size_t)NE * 5;

    // workspace: nbr (N*D f32) | m (N*D f32)
    float* nbr_ws = (float*)d_ws;
    float* m_ws   = nbr_ws + (size_t)NN * D;

    hipMemsetAsync(m_ws, 0, (size_t)NN * D * sizeof(float), stream);

    nbr_kernel<<<NN, 128, 0, stream>>>(z, A_nbr_w, A_nbr_b, nbr_ws);

    edge_msg_kernel<<<EDGE_GRID, 256, 0, stream>>>(
        edge, r, u, W_ndp_w, W_ndp_b, nbr_ws, m_ws,
        rt0_out, rt1_out, rt2_out, c_out);

    node_kernel<<<NN, 128, 0, stream>>>(
        z, A_na_w, A_na_b, m_ws, W_nrd_w, W_nrd_b,
        W_nru_w, W_nru_b, ln_g, ln_b, h_out);

    edge_out_kernel<<<EDGE_GRID, 256, 0, stream>>>(
        edge, r, W_erp_w, W_erp_b, h_out, t_out);
}

// Round 2
// 1417.349 us; speedup vs baseline: 1.2931x; 1.2931x over previous
//
#include <hip/hip_runtime.h>
#include <hip/hip_bf16.h>
#include <math.h>

#define NN 50000
#define NE 1600000
#define D 128
#define NRBF 50
#define RCUT 5.0f
#define LNEPS 1e-5f
#define EB 16
#define EDGE_GRID 2048
#define SCAN_B 196   // ceil(50000/256)

__device__ __forceinline__ float silu_f(float x) {
    return x / (1.0f + __expf(-x));
}

// ---------------------------------------------------------------- kernel 1
// nbr = silu(z @ A_nbr_w + A_nbr_b)
__global__ __launch_bounds__(128) void nbr_kernel(
    const float* __restrict__ z, const float* __restrict__ Aw,
    const float* __restrict__ Ab, float* __restrict__ nbr)
{
    const int n = blockIdx.x;
    const int d = threadIdx.x;
    float acc = Ab[d];
#pragma unroll
    for (int k = 0; k < 25; ++k)
        acc = fmaf(z[n * 25 + k], Aw[k * D + d], acc);
    nbr[(size_t)n * D + d] = silu_f(acc);
}

// ---------------------------------------------------------------- kernel 2
// per-edge aux outputs (rt0, rt1, rt2, c) + degree histogram
__global__ __launch_bounds__(256) void aux_kernel(
    const int* __restrict__ edge, const float* __restrict__ r,
    const float* __restrict__ u, float* __restrict__ rt0,
    float* __restrict__ rt1, float* __restrict__ rt2,
    float* __restrict__ cout, int* __restrict__ cnt)
{
    const int e = blockIdx.x * 256 + threadIdx.x;
    if (e >= NE) return;
    const float rr = r[e];
    rt0[e] = rr;
    const float cc = (rr < RCUT)
        ? 0.5f * (__cosf(3.14159265358979f * rr * (1.0f / RCUT)) + 1.0f)
        : 0.0f;
    cout[e] = cc;
    const float x  = u[e * 3 + 0];
    const float y  = u[e * 3 + 1];
    const float zc = u[e * 3 + 2];
    rt1[(size_t)e * 3 + 0] = x;
    rt1[(size_t)e * 3 + 1] = y;
    rt1[(size_t)e * 3 + 2] = zc;
    const float s3 = 1.7320508075688772f;
    rt2[(size_t)e * 5 + 0] = s3 * x * y;
    rt2[(size_t)e * 5 + 1] = s3 * y * zc;
    rt2[(size_t)e * 5 + 2] = 0.5f * (3.0f * zc * zc - 1.0f);
    rt2[(size_t)e * 5 + 3] = s3 * zc * x;
    rt2[(size_t)e * 5 + 4] = 0.5f * s3 * (x * x - y * y);
    atomicAdd(&cnt[edge[2 * e]], 1);
}

// ---------------------------------------------------------------- scan (3 phases)
__global__ __launch_bounds__(256) void scan1_kernel(
    const int* __restrict__ cnt, int* __restrict__ off, int* __restrict__ bsum)
{
    __shared__ int s[2][256];
    const int t = threadIdx.x;
    const int g = blockIdx.x * 256 + t;
    const int v = (g < NN) ? cnt[g] : 0;
    int incl = v;
    s[0][t] = incl;
    __syncthreads();
    int cur = 0;
#pragma unroll
    for (int dd = 1; dd < 256; dd <<= 1) {
        const int add = (t >= dd) ? s[cur][t - dd] : 0;
        incl += add;
        s[cur ^ 1][t] = incl;
        __syncthreads();
        cur ^= 1;
    }
    if (g < NN) off[g] = incl - v;
    if (t == 255) bsum[blockIdx.x] = incl;
}

__global__ __launch_bounds__(256) void scan2_kernel(int* __restrict__ bsum)
{
    __shared__ int s[2][256];
    const int t = threadIdx.x;
    const int v = (t < SCAN_B) ? bsum[t] : 0;
    int incl = v;
    s[0][t] = incl;
    __syncthreads();
    int cur = 0;
#pragma unroll
    for (int dd = 1; dd < 256; dd <<= 1) {
        const int add = (t >= dd) ? s[cur][t - dd] : 0;
        incl += add;
        s[cur ^ 1][t] = incl;
        __syncthreads();
        cur ^= 1;
    }
    if (t < SCAN_B) bsum[t] = incl - v;   // exclusive
}

__global__ __launch_bounds__(256) void scan3_kernel(
    int* __restrict__ off, const int* __restrict__ bsum)
{
    const int g = blockIdx.x * 256 + threadIdx.x;
    if (g < NN) off[g] += bsum[blockIdx.x];
    if (g == 0) off[NN] = NE;
}

// ---------------------------------------------------------------- scatter
__global__ __launch_bounds__(256) void scatter_kernel(
    const int* __restrict__ edge, const int* __restrict__ off,
    int* __restrict__ cursor, int* __restrict__ elist)
{
    const int e = blockIdx.x * 256 + threadIdx.x;
    if (e >= NE) return;
    const int i = edge[2 * e];
    const int pos = atomicAdd(&cursor[i], 1);
    elist[off[i] + pos] = e;
}

// ---------------------------------------------------------------- gather msg
// m[n,:] = sum over edges e with i==n of nbr[j_e,:] * gate_e
__global__ __launch_bounds__(128) void gather_msg_kernel(
    const int* __restrict__ elist, const int* __restrict__ off,
    const int* __restrict__ edge, const float* __restrict__ r,
    const float* __restrict__ W_ndp, const float* __restrict__ b_ndp,
    const float* __restrict__ nbr, float* __restrict__ m)
{
    __shared__ float rbf_s[EB][56];   // rows 224B (16B aligned); [50..55] = 0
    __shared__ float er_s[EB];
    __shared__ float c_s[EB];
    __shared__ int   j_s[EB];

    const int n = blockIdx.x;
    const int d = threadIdx.x;

    float4 w4[13];
#pragma unroll
    for (int kk = 0; kk < 13; ++kk) {
#pragma unroll
        for (int c = 0; c < 4; ++c) {
            const int k = 4 * kk + c;
            ((float*)&w4[kk])[c] = (k < NRBF) ? W_ndp[k * D + d] : 0.0f;
        }
    }
    const float bd = b_ndp[d];

    const float start = expf(-RCUT);
    const float step  = (1.0f - start) / (NRBF - 1);
    const float bq    = (2.0f / NRBF) * (1.0f - start);
    const float beta  = 1.0f / (bq * bq);

    const int s0  = off[n];
    const int deg = off[n + 1] - s0;

    float macc = 0.0f;
    for (int base = 0; base < deg; base += EB) {
        const int chunk = min(EB, deg - base);
        if (d < EB) {
            if (d < chunk) {
                const int eid = elist[s0 + base + d];
                const float rr = r[eid];
                er_s[d] = __expf(-rr);
                c_s[d] = (rr < RCUT)
                    ? 0.5f * (__cosf(3.14159265358979f * rr * (1.0f / RCUT)) + 1.0f)
                    : 0.0f;
                j_s[d] = edge[2 * eid + 1];
            } else {
                er_s[d] = 0.0f; c_s[d] = 0.0f; j_s[d] = 0;
            }
        }
        __syncthreads();
        for (int idx = d; idx < EB * 64; idx += 128) {
            const int el = idx >> 6;
            const int k  = idx & 63;
            if (k < 56) {
                float v = 0.0f;
                if (el < chunk && k < NRBF) {
                    const float diff = er_s[el] - (start + (float)k * step);
                    v = __expf(-beta * diff * diff);
                }
                rbf_s[el][k] = v;
            }
        }
        __syncthreads();
        // prefetch the 16 nbr gathers
        float nv[EB];
#pragma unroll
        for (int el = 0; el < EB; ++el)
            nv[el] = nbr[(size_t)j_s[el] * D + d];
        // vectorized dot per edge
#pragma unroll
        for (int el = 0; el < EB; ++el) {
            float4 a4 = {0.0f, 0.0f, 0.0f, 0.0f};
#pragma unroll
            for (int kk = 0; kk < 13; ++kk) {
                const float4 rb = *(const float4*)&rbf_s[el][4 * kk];
                a4.x = fmaf(rb.x, w4[kk].x, a4.x);
                a4.y = fmaf(rb.y, w4[kk].y, a4.y);
                a4.z = fmaf(rb.z, w4[kk].z, a4.z);
                a4.w = fmaf(rb.w, w4[kk].w, a4.w);
            }
            const float gate = (a4.x + a4.y + a4.z + a4.w + bd) * c_s[el];
            macc = fmaf(nv[el], gate, macc);
        }
        __syncthreads();
    }
    m[(size_t)n * D + d] = macc;
}

// ---------------------------------------------------------------- node MLP
__global__ __launch_bounds__(128) void node_kernel(
    const float* __restrict__ z, const float* __restrict__ A_na_w,
    const float* __restrict__ A_na_b, const float* __restrict__ m,
    const float* __restrict__ W_nrd_w, const float* __restrict__ W_nrd_b,
    const float* __restrict__ W_nru_w, const float* __restrict__ W_nru_b,
    const float* __restrict__ ln_g, const float* __restrict__ ln_b,
    float* __restrict__ hout)
{
    __shared__ float buf[256];
    __shared__ float red[4];
    const int n = blockIdx.x;
    const int d = threadIdx.x;

    float acc = A_na_b[d];
#pragma unroll
    for (int k = 0; k < 25; ++k)
        acc = fmaf(z[n * 25 + k], A_na_w[k * D + d], acc);
    buf[d]       = silu_f(acc);
    buf[128 + d] = m[(size_t)n * D + d];
    __syncthreads();

    float h1 = W_nrd_b[d];
#pragma unroll 8
    for (int k = 0; k < 256; ++k)
        h1 = fmaf(buf[k], W_nrd_w[k * D + d], h1);

    float s = h1, sq = h1 * h1;
#pragma unroll
    for (int off = 32; off >= 1; off >>= 1) {
        s  += __shfl_xor(s, off);
        sq += __shfl_xor(sq, off);
    }
    const int wv = d >> 6;
    if ((d & 63) == 0) { red[wv] = s; red[2 + wv] = sq; }
    __syncthreads();
    const float tot   = red[0] + red[1];
    const float totsq = red[2] + red[3];
    const float mu  = tot * (1.0f / 128.0f);
    const float var = totsq * (1.0f / 128.0f) - mu * mu;
    const float inv = rsqrtf(var + LNEPS);
    float y = (h1 - mu) * inv * ln_g[d] + ln_b[d];
    y = silu_f(y);
    __syncthreads();
    buf[d] = y;
    __syncthreads();

    float h2 = W_nru_b[d];
#pragma unroll 8
    for (int k = 0; k < 128; ++k)
        h2 = fmaf(buf[k], W_nru_w[k * D + d], h2);
    hout[(size_t)n * D + d] = h2;
}

// ---------------------------------------------------------------- edge out
// t = (h[i]+h[j]) * (rbf @ W_erp + b)
__global__ __launch_bounds__(256) void edge_out_kernel(
    const int* __restrict__ edge, const float* __restrict__ r,
    const float* __restrict__ W_erp, const float* __restrict__ b_erp,
    const float* __restrict__ h, float* __restrict__ t)
{
    __shared__ float rbf_s[EB][56];
    __shared__ float er_s[EB];

    const int tid  = threadIdx.x;
    const int d    = tid & 127;
    const int half = tid >> 7;

    float4 w4[13];
#pragma unroll
    for (int kk = 0; kk < 13; ++kk) {
#pragma unroll
        for (int c = 0; c < 4; ++c) {
            const int k = 4 * kk + c;
            ((float*)&w4[kk])[c] = (k < NRBF) ? W_erp[k * D + d] : 0.0f;
        }
    }
    const float bd = b_erp[d];

    const float start = expf(-RCUT);
    const float step  = (1.0f - start) / (NRBF - 1);
    const float bq    = (2.0f / NRBF) * (1.0f - start);
    const float beta  = 1.0f / (bq * bq);

    const int nbatch = NE / EB;
    for (int batch = blockIdx.x; batch < nbatch; batch += gridDim.x) {
        const int eb = batch * EB;
        if (tid < EB) {
            er_s[tid] = __expf(-r[eb + tid]);
        }
        __syncthreads();
        for (int idx = tid; idx < EB * 64; idx += 256) {
            const int el = idx >> 6;
            const int k  = idx & 63;
            if (k < 56) {
                float v = 0.0f;
                if (k < NRBF) {
                    const float diff = er_s[el] - (start + (float)k * step);
                    v = __expf(-beta * diff * diff);
                }
                rbf_s[el][k] = v;
            }
        }
        __syncthreads();
#pragma unroll
        for (int s = 0; s < 8; ++s) {
            const int el = half * 8 + s;
            const int e  = eb + el;
            const int vi = edge[2 * e];
            const int vj = edge[2 * e + 1];
            const float hv = h[(size_t)vi * D + d] + h[(size_t)vj * D + d];
            float4 a4 = {0.0f, 0.0f, 0.0f, 0.0f};
#pragma unroll
            for (int kk = 0; kk < 13; ++kk) {
                const float4 rb = *(const float4*)&rbf_s[el][4 * kk];
                a4.x = fmaf(rb.x, w4[kk].x, a4.x);
                a4.y = fmaf(rb.y, w4[kk].y, a4.y);
                a4.z = fmaf(rb.z, w4[kk].z, a4.z);
                a4.w = fmaf(rb.w, w4[kk].w, a4.w);
            }
            t[(size_t)e * D + d] = hv * (a4.x + a4.y + a4.z + a4.w + bd);
        }
        __syncthreads();
    }
}

// ---------------------------------------------------------------- launch
extern "C" void kernel_launch(void* const* d_in, const int* in_sizes, int n_in,
                              void* d_out, int out_size, void* d_ws, size_t ws_size,
                              hipStream_t stream) {
    const float* z      = (const float*)d_in[0];
    const int*   edge   = (const int*)d_in[1];
    const float* r      = (const float*)d_in[2];
    const float* u      = (const float*)d_in[3];
    const float* A_na_w  = (const float*)d_in[4];
    const float* A_na_b  = (const float*)d_in[5];
    const float* A_nbr_w = (const float*)d_in[6];
    const float* A_nbr_b = (const float*)d_in[7];
    const float* W_ndp_w = (const float*)d_in[8];
    const float* W_ndp_b = (const float*)d_in[9];
    const float* W_nrd_w = (const float*)d_in[10];
    const float* W_nrd_b = (const float*)d_in[11];
    const float* W_nru_w = (const float*)d_in[12];
    const float* W_nru_b = (const float*)d_in[13];
    const float* W_erp_w = (const float*)d_in[14];
    const float* W_erp_b = (const float*)d_in[15];
    const float* ln_g    = (const float*)d_in[16];
    const float* ln_b    = (const float*)d_in[17];

    float* out = (float*)d_out;
    float* h_out   = out;
    float* t_out   = out + (size_t)NN * D;
    float* rt0_out = t_out + (size_t)NE * D;
    float* rt1_out = rt0_out + (size_t)NE;
    float* rt2_out = rt1_out + (size_t)NE * 3;
    float* c_out   = rt2_out + (size_t)NE * 5;

    // ws: nbr | m  (51.2 MB, proven available)
    float* nbr_ws = (float*)d_ws;
    float* m_ws   = nbr_ws + (size_t)NN * D;

    // CSR scratch lives in the t region of d_out (819 MB, written last by
    // edge_out, all reads of these arrays complete before then).
    int* elist  = (int*)t_out;           // NE
    int* off    = elist + NE;            // NN+1
    int* cursor = off + (NN + 1);        // NN
    int* bsum   = cursor + NN;           // 256

    hipMemsetAsync(cursor, 0, (size_t)NN * sizeof(int), stream);

    nbr_kernel<<<NN, 128, 0, stream>>>(z, A_nbr_w, A_nbr_b, nbr_ws);

    aux_kernel<<<(NE + 255) / 256, 256, 0, stream>>>(
        edge, r, u, rt0_out, rt1_out, rt2_out, c_out, cursor);

    scan1_kernel<<<SCAN_B, 256, 0, stream>>>(cursor, off, bsum);
    scan2_kernel<<<1, 256, 0, stream>>>(bsum);
    scan3_kernel<<<SCAN_B, 256, 0, stream>>>(off, bsum);

    hipMemsetAsync(cursor, 0, (size_t)NN * sizeof(int), stream);

    scatter_kernel<<<(NE + 255) / 256, 256, 0, stream>>>(edge, off, cursor, elist);

    gather_msg_kernel<<<NN, 128, 0, stream>>>(
        elist, off, edge, r, W_ndp_w, W_ndp_b, nbr_ws, m_ws);

    node_kernel<<<NN, 128, 0, stream>>>(
        z, A_na_w, A_na_b, m_ws, W_nrd_w, W_nrd_b,
        W_nru_w, W_nru_b, ln_g, ln_b, h_out);

    edge_out_kernel<<<EDGE_GRID, 256, 0, stream>>>(
        edge, r, W_erp_w, W_erp_b, h_out, t_out);
}

// Round 3
// 1310.536 us; speedup vs baseline: 1.3985x; 1.0815x over previous
//
#include <hip/hip_runtime.h>
#include <hip/hip_bf16.h>
#include <math.h>

#define NN 50000
#define NE 1600000
#define D 128
#define NRBF 50
#define RCUT 5.0f
#define LNEPS 1e-5f
#define EB 16
#define EB2 64
#define EDGE_GRID 2048
#define SCAN_B 196   // ceil(50000/256)
#define NB 16

typedef __attribute__((ext_vector_type(8))) short bf16x8;
typedef __attribute__((ext_vector_type(4))) float f32x4;

__device__ __forceinline__ float silu_f(float x) {
    return x / (1.0f + __expf(-x));
}
__device__ __forceinline__ unsigned short f2bf(float x) {
    __hip_bfloat16 b = __float2bfloat16(x);
    return *reinterpret_cast<unsigned short*>(&b);
}

// ---------------------------------------------------------------- kernel 1
// nbr = silu(z @ A_nbr_w + A_nbr_b)
__global__ __launch_bounds__(128) void nbr_kernel(
    const float* __restrict__ z, const float* __restrict__ Aw,
    const float* __restrict__ Ab, float* __restrict__ nbr)
{
    const int n = blockIdx.x;
    const int d = threadIdx.x;
    float acc = Ab[d];
#pragma unroll
    for (int k = 0; k < 25; ++k)
        acc = fmaf(z[n * 25 + k], Aw[k * D + d], acc);
    nbr[(size_t)n * D + d] = silu_f(acc);
}

// ---------------------------------------------------------------- kernel 2
// per-edge aux outputs (rt0, rt1, rt2, c) + degree histogram
__global__ __launch_bounds__(256) void aux_kernel(
    const int* __restrict__ edge, const float* __restrict__ r,
    const float* __restrict__ u, float* __restrict__ rt0,
    float* __restrict__ rt1, float* __restrict__ rt2,
    float* __restrict__ cout, int* __restrict__ cnt)
{
    const int e = blockIdx.x * 256 + threadIdx.x;
    if (e >= NE) return;
    const float rr = r[e];
    rt0[e] = rr;
    const float cc = (rr < RCUT)
        ? 0.5f * (__cosf(3.14159265358979f * rr * (1.0f / RCUT)) + 1.0f)
        : 0.0f;
    cout[e] = cc;
    const float x  = u[e * 3 + 0];
    const float y  = u[e * 3 + 1];
    const float zc = u[e * 3 + 2];
    rt1[(size_t)e * 3 + 0] = x;
    rt1[(size_t)e * 3 + 1] = y;
    rt1[(size_t)e * 3 + 2] = zc;
    const float s3 = 1.7320508075688772f;
    rt2[(size_t)e * 5 + 0] = s3 * x * y;
    rt2[(size_t)e * 5 + 1] = s3 * y * zc;
    rt2[(size_t)e * 5 + 2] = 0.5f * (3.0f * zc * zc - 1.0f);
    rt2[(size_t)e * 5 + 3] = s3 * zc * x;
    rt2[(size_t)e * 5 + 4] = 0.5f * s3 * (x * x - y * y);
    atomicAdd(&cnt[edge[2 * e]], 1);
}

// ---------------------------------------------------------------- scan (3 phases)
__global__ __launch_bounds__(256) void scan1_kernel(
    const int* __restrict__ cnt, int* __restrict__ off, int* __restrict__ bsum)
{
    __shared__ int s[2][256];
    const int t = threadIdx.x;
    const int g = blockIdx.x * 256 + t;
    const int v = (g < NN) ? cnt[g] : 0;
    int incl = v;
    s[0][t] = incl;
    __syncthreads();
    int cur = 0;
#pragma unroll
    for (int dd = 1; dd < 256; dd <<= 1) {
        const int add = (t >= dd) ? s[cur][t - dd] : 0;
        incl += add;
        s[cur ^ 1][t] = incl;
        __syncthreads();
        cur ^= 1;
    }
    if (g < NN) off[g] = incl - v;
    if (t == 255) bsum[blockIdx.x] = incl;
}

__global__ __launch_bounds__(256) void scan2_kernel(int* __restrict__ bsum)
{
    __shared__ int s[2][256];
    const int t = threadIdx.x;
    const int v = (t < SCAN_B) ? bsum[t] : 0;
    int incl = v;
    s[0][t] = incl;
    __syncthreads();
    int cur = 0;
#pragma unroll
    for (int dd = 1; dd < 256; dd <<= 1) {
        const int add = (t >= dd) ? s[cur][t - dd] : 0;
        incl += add;
        s[cur ^ 1][t] = incl;
        __syncthreads();
        cur ^= 1;
    }
    if (t < SCAN_B) bsum[t] = incl - v;   // exclusive
}

__global__ __launch_bounds__(256) void scan3_kernel(
    int* __restrict__ off, const int* __restrict__ bsum)
{
    const int g = blockIdx.x * 256 + threadIdx.x;
    if (g < NN) off[g] += bsum[blockIdx.x];
    if (g == 0) off[NN] = NE;
}

// ---------------------------------------------------------------- scatter
__global__ __launch_bounds__(256) void scatter_kernel(
    const int* __restrict__ edge, const int* __restrict__ off,
    int* __restrict__ cursor, int* __restrict__ elist)
{
    const int e = blockIdx.x * 256 + threadIdx.x;
    if (e >= NE) return;
    const int i = edge[2 * e];
    const int pos = atomicAdd(&cursor[i], 1);
    elist[off[i] + pos] = e;
}

// ---------------------------------------------------------------- gather msg
__global__ __launch_bounds__(128) void gather_msg_kernel(
    const int* __restrict__ elist, const int* __restrict__ off,
    const int* __restrict__ edge, const float* __restrict__ r,
    const float* __restrict__ W_ndp, const float* __restrict__ b_ndp,
    const float* __restrict__ nbr, float* __restrict__ m)
{
    __shared__ float rbf_s[EB][56];
    __shared__ float er_s[EB];
    __shared__ float c_s[EB];
    __shared__ int   j_s[EB];

    const int n = blockIdx.x;
    const int d = threadIdx.x;

    float4 w4[13];
#pragma unroll
    for (int kk = 0; kk < 13; ++kk) {
#pragma unroll
        for (int c = 0; c < 4; ++c) {
            const int k = 4 * kk + c;
            ((float*)&w4[kk])[c] = (k < NRBF) ? W_ndp[k * D + d] : 0.0f;
        }
    }
    const float bd = b_ndp[d];

    const float start = expf(-RCUT);
    const float step  = (1.0f - start) / (NRBF - 1);
    const float bq    = (2.0f / NRBF) * (1.0f - start);
    const float beta  = 1.0f / (bq * bq);

    const int s0  = off[n];
    const int deg = off[n + 1] - s0;

    float macc = 0.0f;
    for (int base = 0; base < deg; base += EB) {
        const int chunk = min(EB, deg - base);
        if (d < EB) {
            if (d < chunk) {
                const int eid = elist[s0 + base + d];
                const float rr = r[eid];
                er_s[d] = __expf(-rr);
                c_s[d] = (rr < RCUT)
                    ? 0.5f * (__cosf(3.14159265358979f * rr * (1.0f / RCUT)) + 1.0f)
                    : 0.0f;
                j_s[d] = edge[2 * eid + 1];
            } else {
                er_s[d] = 0.0f; c_s[d] = 0.0f; j_s[d] = 0;
            }
        }
        __syncthreads();
        for (int idx = d; idx < EB * 64; idx += 128) {
            const int el = idx >> 6;
            const int k  = idx & 63;
            if (k < 56) {
                float v = 0.0f;
                if (el < chunk && k < NRBF) {
                    const float diff = er_s[el] - (start + (float)k * step);
                    v = __expf(-beta * diff * diff);
                }
                rbf_s[el][k] = v;
            }
        }
        __syncthreads();
        float nv[EB];
#pragma unroll
        for (int el = 0; el < EB; ++el)
            nv[el] = nbr[(size_t)j_s[el] * D + d];
#pragma unroll
        for (int el = 0; el < EB; ++el) {
            float4 a4 = {0.0f, 0.0f, 0.0f, 0.0f};
#pragma unroll
            for (int kk = 0; kk < 13; ++kk) {
                const float4 rb = *(const float4*)&rbf_s[el][4 * kk];
                a4.x = fmaf(rb.x, w4[kk].x, a4.x);
                a4.y = fmaf(rb.y, w4[kk].y, a4.y);
                a4.z = fmaf(rb.z, w4[kk].z, a4.z);
                a4.w = fmaf(rb.w, w4[kk].w, a4.w);
            }
            const float gate = (a4.x + a4.y + a4.z + a4.w + bd) * c_s[el];
            macc = fmaf(nv[el], gate, macc);
        }
        __syncthreads();
    }
    m[(size_t)n * D + d] = macc;
}

// ---------------------------------------------------------------- node MLP
// 16 nodes per block; weights staged in LDS in 32-row tiles.
// thread map: nl = tid&15 (node), dg = tid>>4 (d-group of 8)
__global__ __launch_bounds__(256) void node_kernel2(
    const float* __restrict__ z, const float* __restrict__ A_na_w,
    const float* __restrict__ A_na_b, const float* __restrict__ m,
    const float* __restrict__ W_nrd_w, const float* __restrict__ W_nrd_b,
    const float* __restrict__ W_nru_w, const float* __restrict__ W_nru_b,
    const float* __restrict__ ln_g, const float* __restrict__ ln_b,
    float* __restrict__ hout)
{
    __shared__ float inbuf[NB][260];   // [n][k], padded (bank spread)
    __shared__ float wbuf[32][128];    // staged weight tile
    __shared__ float part[4][NB][2];   // per-wave LN partials

    const int tid = threadIdx.x;
    const int n0 = blockIdx.x * NB;
    const int nl = tid & 15;
    const int dg = tid >> 4;

    // phase 0: inbuf[n][0..127] = na, [128..255] = m
    for (int idx = tid; idx < NB * 128; idx += 256) {
        const int n = idx >> 7;
        const int d = idx & 127;
        float acc = A_na_b[d];
#pragma unroll
        for (int k = 0; k < 25; ++k)
            acc = fmaf(z[(size_t)(n0 + n) * 25 + k], A_na_w[k * D + d], acc);
        inbuf[n][d]       = silu_f(acc);
        inbuf[n][128 + d] = m[(size_t)(n0 + n) * D + d];
    }

    float h1[8];
#pragma unroll
    for (int dd = 0; dd < 8; ++dd) h1[dd] = W_nrd_b[dg * 8 + dd];

    for (int tile = 0; tile < 8; ++tile) {
        __syncthreads();
        for (int v = tid; v < 32 * 32; v += 256) {
            const int row = v >> 5;
            const int c4  = (v & 31) * 4;
            *(float4*)&wbuf[row][c4] =
                *(const float4*)&W_nrd_w[(size_t)(tile * 32 + row) * D + c4];
        }
        __syncthreads();
#pragma unroll 4
        for (int k = 0; k < 32; ++k) {
            const float rin = inbuf[nl][tile * 32 + k];
            const float4 wa = *(const float4*)&wbuf[k][dg * 8];
            const float4 wb = *(const float4*)&wbuf[k][dg * 8 + 4];
            h1[0] = fmaf(rin, wa.x, h1[0]);
            h1[1] = fmaf(rin, wa.y, h1[1]);
            h1[2] = fmaf(rin, wa.z, h1[2]);
            h1[3] = fmaf(rin, wa.w, h1[3]);
            h1[4] = fmaf(rin, wb.x, h1[4]);
            h1[5] = fmaf(rin, wb.y, h1[5]);
            h1[6] = fmaf(rin, wb.z, h1[6]);
            h1[7] = fmaf(rin, wb.w, h1[7]);
        }
    }

    // LayerNorm stats: reduce 8 local + across dg
    float s = 0.0f, sq = 0.0f;
#pragma unroll
    for (int dd = 0; dd < 8; ++dd) { s += h1[dd]; sq += h1[dd] * h1[dd]; }
    s  += __shfl_xor(s, 16);  sq += __shfl_xor(sq, 16);
    s  += __shfl_xor(s, 32);  sq += __shfl_xor(sq, 32);
    const int wv = tid >> 6;
    if ((tid & 63) < 16) { part[wv][nl][0] = s; part[wv][nl][1] = sq; }
    __syncthreads();
    float ts = 0.0f, tsq = 0.0f;
#pragma unroll
    for (int w = 0; w < 4; ++w) { ts += part[w][nl][0]; tsq += part[w][nl][1]; }
    const float mu  = ts * (1.0f / 128.0f);
    const float var = tsq * (1.0f / 128.0f) - mu * mu;
    const float inv = rsqrtf(var + LNEPS);

    // y = silu(LN(h1)) -> back into inbuf[n][0..127]
#pragma unroll
    for (int dd = 0; dd < 8; ++dd) {
        const int d = dg * 8 + dd;
        inbuf[nl][d] = silu_f((h1[dd] - mu) * inv * ln_g[d] + ln_b[d]);
    }

    float h2[8];
#pragma unroll
    for (int dd = 0; dd < 8; ++dd) h2[dd] = W_nru_b[dg * 8 + dd];

    for (int tile = 0; tile < 4; ++tile) {
        __syncthreads();
        for (int v = tid; v < 32 * 32; v += 256) {
            const int row = v >> 5;
            const int c4  = (v & 31) * 4;
            *(float4*)&wbuf[row][c4] =
                *(const float4*)&W_nru_w[(size_t)(tile * 32 + row) * D + c4];
        }
        __syncthreads();
#pragma unroll 4
        for (int k = 0; k < 32; ++k) {
            const float rin = inbuf[nl][tile * 32 + k];
            const float4 wa = *(const float4*)&wbuf[k][dg * 8];
            const float4 wb = *(const float4*)&wbuf[k][dg * 8 + 4];
            h2[0] = fmaf(rin, wa.x, h2[0]);
            h2[1] = fmaf(rin, wa.y, h2[1]);
            h2[2] = fmaf(rin, wa.z, h2[2]);
            h2[3] = fmaf(rin, wa.w, h2[3]);
            h2[4] = fmaf(rin, wb.x, h2[4]);
            h2[5] = fmaf(rin, wb.y, h2[5]);
            h2[6] = fmaf(rin, wb.z, h2[6]);
            h2[7] = fmaf(rin, wb.w, h2[7]);
        }
    }

    float4 o0 = {h2[0], h2[1], h2[2], h2[3]};
    float4 o1 = {h2[4], h2[5], h2[6], h2[7]};
    *(float4*)&hout[(size_t)(n0 + nl) * D + dg * 8]     = o0;
    *(float4*)&hout[(size_t)(n0 + nl) * D + dg * 8 + 4] = o1;
}

// ---------------------------------------------------------------- edge out (MFMA)
// t = (h[i]+h[j]) * (rbf @ W_erp + b), rbf@W via bf16 MFMA 16x16x32.
// Block = 4 waves; wave w handles edges [eb + w*16, +16) x all 128 d.
__global__ __launch_bounds__(256) void edge_out_mfma(
    const int* __restrict__ edge, const float* __restrict__ r,
    const float* __restrict__ W_erp, const float* __restrict__ b_erp,
    const float* __restrict__ h, float* __restrict__ t)
{
    __shared__ unsigned short P[EB2][64];  // bf16 rbf, 16B-chunk XOR swizzle
    __shared__ int ij_s[EB2][2];

    const int tid = threadIdx.x;
    const int w  = tid >> 6;
    const int l  = tid & 63;
    const int lr = l & 15;   // row-in-tile (A) / col (B, C)
    const int lg = l >> 4;   // k-group

    // W_erp fragments (B operand) + bias, in registers
    bf16x8 wf[8][2];
    float bias[8];
#pragma unroll
    for (int dt = 0; dt < 8; ++dt) {
        const int col = dt * 16 + lr;
        bias[dt] = b_erp[col];
#pragma unroll
        for (int s = 0; s < 2; ++s) {
            bf16x8 v;
#pragma unroll
            for (int j = 0; j < 8; ++j) {
                const int k = s * 32 + lg * 8 + j;
                v[j] = (k < NRBF) ? (short)f2bf(W_erp[k * D + col]) : (short)0;
            }
            wf[dt][s] = v;
        }
    }

    const float start = expf(-RCUT);
    const float step  = (1.0f - start) / (NRBF - 1);
    const float bq    = (2.0f / NRBF) * (1.0f - start);
    const float beta  = 1.0f / (bq * bq);

    const int prow  = tid & 63;        // P row filled by this thread
    const int kbase = (tid >> 6) * 16; // 16 k values per thread

    const int nbatch = NE / EB2;
    for (int batch = blockIdx.x; batch < nbatch; batch += gridDim.x) {
        const int eb = batch * EB2;
        if (tid < EB2) {
            const int2 ep = ((const int2*)edge)[eb + tid];
            ij_s[tid][0] = ep.x;
            ij_s[tid][1] = ep.y;
        }
        {
            const float er = __expf(-r[eb + prow]);
#pragma unroll
            for (int kk = 0; kk < 16; kk += 2) {
                const int k0 = kbase + kk;
                unsigned int pk = 0;
#pragma unroll
                for (int c = 0; c < 2; ++c) {
                    const int k = k0 + c;
                    float v = 0.0f;
                    if (k < NRBF) {
                        const float diff = er - (start + (float)k * step);
                        v = __expf(-beta * diff * diff);
                    }
                    pk |= ((unsigned int)f2bf(v)) << (16 * c);
                }
                const int swc = (k0 >> 3) ^ (prow & 7);
                *(unsigned int*)&P[prow][swc * 8 + (k0 & 7)] = pk;
            }
        }
        __syncthreads();

        const int arow = w * 16 + lr;
        bf16x8 af[2];
#pragma unroll
        for (int s = 0; s < 2; ++s) {
            const int swc = (s * 4 + lg) ^ (arow & 7);
            af[s] = *(const bf16x8*)&P[arow][swc * 8];
        }
        int vi[4], vj[4];
#pragma unroll
        for (int q = 0; q < 4; ++q) {
            const int erow = w * 16 + lg * 4 + q;
            vi[q] = ij_s[erow][0];
            vj[q] = ij_s[erow][1];
        }
#pragma unroll
        for (int dt = 0; dt < 8; ++dt) {
            f32x4 acc = {0.0f, 0.0f, 0.0f, 0.0f};
            acc = __builtin_amdgcn_mfma_f32_16x16x32_bf16(af[0], wf[dt][0], acc, 0, 0, 0);
            acc = __builtin_amdgcn_mfma_f32_16x16x32_bf16(af[1], wf[dt][1], acc, 0, 0, 0);
            const int col = dt * 16 + lr;
#pragma unroll
            for (int q = 0; q < 4; ++q) {
                const int e = eb + w * 16 + lg * 4 + q;
                const float hv = h[(size_t)vi[q] * D + col] + h[(size_t)vj[q] * D + col];
                t[(size_t)e * D + col] = hv * (acc[q] + bias[dt]);
            }
        }
        __syncthreads();
    }
}

// ---------------------------------------------------------------- launch
extern "C" void kernel_launch(void* const* d_in, const int* in_sizes, int n_in,
                              void* d_out, int out_size, void* d_ws, size_t ws_size,
                              hipStream_t stream) {
    const float* z      = (const float*)d_in[0];
    const int*   edge   = (const int*)d_in[1];
    const float* r      = (const float*)d_in[2];
    const float* u      = (const float*)d_in[3];
    const float* A_na_w  = (const float*)d_in[4];
    const float* A_na_b  = (const float*)d_in[5];
    const float* A_nbr_w = (const float*)d_in[6];
    const float* A_nbr_b = (const float*)d_in[7];
    const float* W_ndp_w = (const float*)d_in[8];
    const float* W_ndp_b = (const float*)d_in[9];
    const float* W_nrd_w = (const float*)d_in[10];
    const float* W_nrd_b = (const float*)d_in[11];
    const float* W_nru_w = (const float*)d_in[12];
    const float* W_nru_b = (const float*)d_in[13];
    const float* W_erp_w = (const float*)d_in[14];
    const float* W_erp_b = (const float*)d_in[15];
    const float* ln_g    = (const float*)d_in[16];
    const float* ln_b    = (const float*)d_in[17];

    float* out = (float*)d_out;
    float* h_out   = out;
    float* t_out   = out + (size_t)NN * D;
    float* rt0_out = t_out + (size_t)NE * D;
    float* rt1_out = rt0_out + (size_t)NE;
    float* rt2_out = rt1_out + (size_t)NE * 3;
    float* c_out   = rt2_out + (size_t)NE * 5;

    float* nbr_ws = (float*)d_ws;
    float* m_ws   = nbr_ws + (size_t)NN * D;

    // CSR scratch in the (written-last) t region of d_out
    int* elist  = (int*)t_out;           // NE
    int* off    = elist + NE;            // NN+1
    int* cursor = off + (NN + 1);        // NN
    int* bsum   = cursor + NN;           // 256

    hipMemsetAsync(cursor, 0, (size_t)NN * sizeof(int), stream);

    nbr_kernel<<<NN, 128, 0, stream>>>(z, A_nbr_w, A_nbr_b, nbr_ws);

    aux_kernel<<<(NE + 255) / 256, 256, 0, stream>>>(
        edge, r, u, rt0_out, rt1_out, rt2_out, c_out, cursor);

    scan1_kernel<<<SCAN_B, 256, 0, stream>>>(cursor, off, bsum);
    scan2_kernel<<<1, 256, 0, stream>>>(bsum);
    scan3_kernel<<<SCAN_B, 256, 0, stream>>>(off, bsum);

    hipMemsetAsync(cursor, 0, (size_t)NN * sizeof(int), stream);

    scatter_kernel<<<(NE + 255) / 256, 256, 0, stream>>>(edge, off, cursor, elist);

    gather_msg_kernel<<<NN, 128, 0, stream>>>(
        elist, off, edge, r, W_ndp_w, W_ndp_b, nbr_ws, m_ws);

    node_kernel2<<<NN / NB, 256, 0, stream>>>(
        z, A_na_w, A_na_b, m_ws, W_nrd_w, W_nrd_b,
        W_nru_w, W_nru_b, ln_g, ln_b, h_out);

    edge_out_mfma<<<EDGE_GRID, 256, 0, stream>>>(
        edge, r, W_erp_w, W_erp_b, h_out, t_out);
}

// Round 4
// 1222.065 us; speedup vs baseline: 1.4997x; 1.0724x over previous
//
#include <hip/hip_runtime.h>
#include <hip/hip_bf16.h>
#include <math.h>

#define NN 50000
#define NE 1600000
#define D 128
#define NRBF 50
#define RCUT 5.0f
#define LNEPS 1e-5f
#define EB 16
#define EB2 64
#define EDGE_GRID 2048
#define SCAN_B 196   // ceil(50000/256)
#define NB 16

typedef __attribute__((ext_vector_type(8))) short bf16x8;
typedef __attribute__((ext_vector_type(4))) float f32x4;

__device__ __forceinline__ float silu_f(float x) {
    return x / (1.0f + __expf(-x));
}
__device__ __forceinline__ unsigned short f2bf(float x) {
    __hip_bfloat16 b = __float2bfloat16(x);
    return *reinterpret_cast<unsigned short*>(&b);
}

// ---------------------------------------------------------------- kernel 1
__global__ __launch_bounds__(128) void nbr_kernel(
    const float* __restrict__ z, const float* __restrict__ Aw,
    const float* __restrict__ Ab, float* __restrict__ nbr)
{
    const int n = blockIdx.x;
    const int d = threadIdx.x;
    float acc = Ab[d];
#pragma unroll
    for (int k = 0; k < 25; ++k)
        acc = fmaf(z[n * 25 + k], Aw[k * D + d], acc);
    nbr[(size_t)n * D + d] = silu_f(acc);
}

// ---------------------------------------------------------------- kernel 2
__global__ __launch_bounds__(256) void aux_kernel(
    const int* __restrict__ edge, const float* __restrict__ r,
    const float* __restrict__ u, float* __restrict__ rt0,
    float* __restrict__ rt1, float* __restrict__ rt2,
    float* __restrict__ cout, int* __restrict__ cnt)
{
    const int e = blockIdx.x * 256 + threadIdx.x;
    if (e >= NE) return;
    const float rr = r[e];
    rt0[e] = rr;
    const float cc = (rr < RCUT)
        ? 0.5f * (__cosf(3.14159265358979f * rr * (1.0f / RCUT)) + 1.0f)
        : 0.0f;
    cout[e] = cc;
    const float x  = u[e * 3 + 0];
    const float y  = u[e * 3 + 1];
    const float zc = u[e * 3 + 2];
    rt1[(size_t)e * 3 + 0] = x;
    rt1[(size_t)e * 3 + 1] = y;
    rt1[(size_t)e * 3 + 2] = zc;
    const float s3 = 1.7320508075688772f;
    rt2[(size_t)e * 5 + 0] = s3 * x * y;
    rt2[(size_t)e * 5 + 1] = s3 * y * zc;
    rt2[(size_t)e * 5 + 2] = 0.5f * (3.0f * zc * zc - 1.0f);
    rt2[(size_t)e * 5 + 3] = s3 * zc * x;
    rt2[(size_t)e * 5 + 4] = 0.5f * s3 * (x * x - y * y);
    atomicAdd(&cnt[edge[2 * e]], 1);
}

// ---------------------------------------------------------------- scans
__global__ __launch_bounds__(256) void scan1_kernel(
    const int* __restrict__ cnt, int* __restrict__ off, int* __restrict__ bsum)
{
    __shared__ int s[2][256];
    const int t = threadIdx.x;
    const int g = blockIdx.x * 256 + t;
    const int v = (g < NN) ? cnt[g] : 0;
    int incl = v;
    s[0][t] = incl;
    __syncthreads();
    int cur = 0;
#pragma unroll
    for (int dd = 1; dd < 256; dd <<= 1) {
        const int add = (t >= dd) ? s[cur][t - dd] : 0;
        incl += add;
        s[cur ^ 1][t] = incl;
        __syncthreads();
        cur ^= 1;
    }
    if (g < NN) off[g] = incl - v;
    if (t == 255) bsum[blockIdx.x] = incl;
}

__global__ __launch_bounds__(256) void scan2_kernel(int* __restrict__ bsum)
{
    __shared__ int s[2][256];
    const int t = threadIdx.x;
    const int v = (t < SCAN_B) ? bsum[t] : 0;
    int incl = v;
    s[0][t] = incl;
    __syncthreads();
    int cur = 0;
#pragma unroll
    for (int dd = 1; dd < 256; dd <<= 1) {
        const int add = (t >= dd) ? s[cur][t - dd] : 0;
        incl += add;
        s[cur ^ 1][t] = incl;
        __syncthreads();
        cur ^= 1;
    }
    if (t < SCAN_B) bsum[t] = incl - v;
}

__global__ __launch_bounds__(256) void scan3_kernel(
    int* __restrict__ off, const int* __restrict__ bsum)
{
    const int g = blockIdx.x * 256 + threadIdx.x;
    if (g < NN) off[g] += bsum[blockIdx.x];
    if (g == 0) off[NN] = NE;
}

// ---------------------------------------------------------------- scatter
__global__ __launch_bounds__(256) void scatter_kernel(
    const int* __restrict__ edge, const int* __restrict__ off,
    int* __restrict__ cursor, int* __restrict__ elist)
{
    const int e = blockIdx.x * 256 + threadIdx.x;
    if (e >= NE) return;
    const int i = edge[2 * e];
    const int pos = atomicAdd(&cursor[i], 1);
    elist[off[i] + pos] = e;
}

// ---------------------------------------------------------------- gather msg (MFMA)
// m[n,:] = sum_e nbr[j_e,:] * gate_e[:]
// gate computed as 16x16x32 bf16 MFMA:  P(16 edges x 64 K) @ Wf(64 K x 128 d)
// P rows pre-scaled by cutoff c; K row 50 holds c so W row 50 = bias folds in.
__global__ __launch_bounds__(128) void gather_msg_mfma(
    const int* __restrict__ elist, const int* __restrict__ off,
    const int* __restrict__ edge, const float* __restrict__ r,
    const float* __restrict__ W_ndp, const float* __restrict__ b_ndp,
    const float* __restrict__ nbr, float* __restrict__ m)
{
    __shared__ unsigned short P[EB][64];   // bf16, 16B-chunk XOR swizzle per row
    __shared__ float er_s[EB];
    __shared__ float c_s[EB];
    __shared__ int   j_s[EB];

    const int tid = threadIdx.x;
    const int w   = tid >> 6;      // wave (0..1): cols w*64 .. w*64+63
    const int l   = tid & 63;
    const int lr  = l & 15;        // col-in-tile / A-row
    const int lg  = l >> 4;        // k-group / C row-group

    // W fragments: 4 col-tiles x 2 K-slices, row 50 = bias, rows 51..63 = 0
    bf16x8 wf[4][2];
#pragma unroll
    for (int dt = 0; dt < 4; ++dt) {
        const int col = w * 64 + dt * 16 + lr;
#pragma unroll
        for (int s = 0; s < 2; ++s) {
            bf16x8 v;
#pragma unroll
            for (int j = 0; j < 8; ++j) {
                const int k = s * 32 + lg * 8 + j;
                float wv = 0.0f;
                if (k < NRBF)       wv = W_ndp[k * D + col];
                else if (k == NRBF) wv = b_ndp[col];
                v[j] = (short)f2bf(wv);
            }
            wf[dt][s] = v;
        }
    }

    const float start = expf(-RCUT);
    const float step  = (1.0f - start) / (NRBF - 1);
    const float bq    = (2.0f / NRBF) * (1.0f - start);
    const float beta  = 1.0f / (bq * bq);

    const int n   = blockIdx.x;
    const int s0  = off[n];
    const int deg = off[n + 1] - s0;

    const int prow = tid >> 3;       // P row this thread fills (0..15)
    const int pci  = tid & 7;        // 16B chunk (8 halfs) within row

    f32x4 macc[4] = {{0,0,0,0},{0,0,0,0},{0,0,0,0},{0,0,0,0}};

    for (int base = 0; base < deg; base += EB) {
        const int chunk = min(EB, deg - base);
        // phase A: per-edge scalars (16 lanes)
        if (tid < EB) {
            if (tid < chunk) {
                const int eid = elist[s0 + base + tid];
                const float rr = r[eid];
                er_s[tid] = __expf(-rr);
                c_s[tid] = (rr < RCUT)
                    ? 0.5f * (__cosf(3.14159265358979f * rr * (1.0f / RCUT)) + 1.0f)
                    : 0.0f;
                j_s[tid] = edge[2 * eid + 1];
            } else {
                er_s[tid] = 0.0f; c_s[tid] = 0.0f; j_s[tid] = 0;
            }
        }
        __syncthreads();
        // phase B: fill P (each thread one 16B chunk = 8 bf16)
        {
            const float er = er_s[prow];
            const float cc = c_s[prow];
            unsigned int pk[4];
#pragma unroll
            for (int p2 = 0; p2 < 4; ++p2) {
                unsigned int word = 0;
#pragma unroll
                for (int c = 0; c < 2; ++c) {
                    const int k = pci * 8 + p2 * 2 + c;
                    float v = 0.0f;
                    if (k < NRBF) {
                        const float diff = er - (start + (float)k * step);
                        v = cc * __expf(-beta * diff * diff);
                    } else if (k == NRBF) {
                        v = cc;
                    }
                    word |= ((unsigned int)f2bf(v)) << (16 * c);
                }
                pk[p2] = word;
            }
            const int swc = pci ^ (prow & 7);
            *(uint4*)&P[prow][swc * 8] = make_uint4(pk[0], pk[1], pk[2], pk[3]);
        }
        __syncthreads();
        // phase C: A-fragments, MFMA, epilogue
        bf16x8 af[2];
#pragma unroll
        for (int s = 0; s < 2; ++s) {
            const int swc = (s * 4 + lg) ^ (lr & 7);
            af[s] = *(const bf16x8*)&P[lr][swc * 8];
        }
        int jrow[4];
#pragma unroll
        for (int q = 0; q < 4; ++q) jrow[q] = j_s[lg * 4 + q];
#pragma unroll
        for (int dt = 0; dt < 4; ++dt) {
            f32x4 acc = {0.0f, 0.0f, 0.0f, 0.0f};
            acc = __builtin_amdgcn_mfma_f32_16x16x32_bf16(af[0], wf[dt][0], acc, 0, 0, 0);
            acc = __builtin_amdgcn_mfma_f32_16x16x32_bf16(af[1], wf[dt][1], acc, 0, 0, 0);
            const int col = w * 64 + dt * 16 + lr;
#pragma unroll
            for (int q = 0; q < 4; ++q) {
                const float nv = nbr[(size_t)jrow[q] * D + col];
                macc[dt][q] = fmaf(nv, acc[q], macc[dt][q]);
            }
        }
        __syncthreads();
    }

    // reduce the 4 q-partials per lane, then across lg groups
#pragma unroll
    for (int dt = 0; dt < 4; ++dt) {
        float v = macc[dt][0] + macc[dt][1] + macc[dt][2] + macc[dt][3];
        v += __shfl_xor(v, 16);
        v += __shfl_xor(v, 32);
        if (lg == 0)
            m[(size_t)n * D + w * 64 + dt * 16 + lr] = v;
    }
}

// ---------------------------------------------------------------- node MLP
__global__ __launch_bounds__(256) void node_kernel2(
    const float* __restrict__ z, const float* __restrict__ A_na_w,
    const float* __restrict__ A_na_b, const float* __restrict__ m,
    const float* __restrict__ W_nrd_w, const float* __restrict__ W_nrd_b,
    const float* __restrict__ W_nru_w, const float* __restrict__ W_nru_b,
    const float* __restrict__ ln_g, const float* __restrict__ ln_b,
    float* __restrict__ hout)
{
    __shared__ float inbuf[NB][260];
    __shared__ float wbuf[32][128];
    __shared__ float part[4][NB][2];

    const int tid = threadIdx.x;
    const int n0 = blockIdx.x * NB;
    const int nl = tid & 15;
    const int dg = tid >> 4;

    for (int idx = tid; idx < NB * 128; idx += 256) {
        const int n = idx >> 7;
        const int d = idx & 127;
        float acc = A_na_b[d];
#pragma unroll
        for (int k = 0; k < 25; ++k)
            acc = fmaf(z[(size_t)(n0 + n) * 25 + k], A_na_w[k * D + d], acc);
        inbuf[n][d]       = silu_f(acc);
        inbuf[n][128 + d] = m[(size_t)(n0 + n) * D + d];
    }

    float h1[8];
#pragma unroll
    for (int dd = 0; dd < 8; ++dd) h1[dd] = W_nrd_b[dg * 8 + dd];

    for (int tile = 0; tile < 8; ++tile) {
        __syncthreads();
        for (int v = tid; v < 32 * 32; v += 256) {
            const int row = v >> 5;
            const int c4  = (v & 31) * 4;
            *(float4*)&wbuf[row][c4] =
                *(const float4*)&W_nrd_w[(size_t)(tile * 32 + row) * D + c4];
        }
        __syncthreads();
#pragma unroll 4
        for (int k = 0; k < 32; ++k) {
            const float rin = inbuf[nl][tile * 32 + k];
            const float4 wa = *(const float4*)&wbuf[k][dg * 8];
            const float4 wb = *(const float4*)&wbuf[k][dg * 8 + 4];
            h1[0] = fmaf(rin, wa.x, h1[0]);
            h1[1] = fmaf(rin, wa.y, h1[1]);
            h1[2] = fmaf(rin, wa.z, h1[2]);
            h1[3] = fmaf(rin, wa.w, h1[3]);
            h1[4] = fmaf(rin, wb.x, h1[4]);
            h1[5] = fmaf(rin, wb.y, h1[5]);
            h1[6] = fmaf(rin, wb.z, h1[6]);
            h1[7] = fmaf(rin, wb.w, h1[7]);
        }
    }

    float s = 0.0f, sq = 0.0f;
#pragma unroll
    for (int dd = 0; dd < 8; ++dd) { s += h1[dd]; sq += h1[dd] * h1[dd]; }
    s  += __shfl_xor(s, 16);  sq += __shfl_xor(sq, 16);
    s  += __shfl_xor(s, 32);  sq += __shfl_xor(sq, 32);
    const int wv = tid >> 6;
    if ((tid & 63) < 16) { part[wv][nl][0] = s; part[wv][nl][1] = sq; }
    __syncthreads();
    float ts = 0.0f, tsq = 0.0f;
#pragma unroll
    for (int w = 0; w < 4; ++w) { ts += part[w][nl][0]; tsq += part[w][nl][1]; }
    const float mu  = ts * (1.0f / 128.0f);
    const float var = tsq * (1.0f / 128.0f) - mu * mu;
    const float inv = rsqrtf(var + LNEPS);

#pragma unroll
    for (int dd = 0; dd < 8; ++dd) {
        const int d = dg * 8 + dd;
        inbuf[nl][d] = silu_f((h1[dd] - mu) * inv * ln_g[d] + ln_b[d]);
    }

    float h2[8];
#pragma unroll
    for (int dd = 0; dd < 8; ++dd) h2[dd] = W_nru_b[dg * 8 + dd];

    for (int tile = 0; tile < 4; ++tile) {
        __syncthreads();
        for (int v = tid; v < 32 * 32; v += 256) {
            const int row = v >> 5;
            const int c4  = (v & 31) * 4;
            *(float4*)&wbuf[row][c4] =
                *(const float4*)&W_nru_w[(size_t)(tile * 32 + row) * D + c4];
        }
        __syncthreads();
#pragma unroll 4
        for (int k = 0; k < 32; ++k) {
            const float rin = inbuf[nl][tile * 32 + k];
            const float4 wa = *(const float4*)&wbuf[k][dg * 8];
            const float4 wb = *(const float4*)&wbuf[k][dg * 8 + 4];
            h2[0] = fmaf(rin, wa.x, h2[0]);
            h2[1] = fmaf(rin, wa.y, h2[1]);
            h2[2] = fmaf(rin, wa.z, h2[2]);
            h2[3] = fmaf(rin, wa.w, h2[3]);
            h2[4] = fmaf(rin, wb.x, h2[4]);
            h2[5] = fmaf(rin, wb.y, h2[5]);
            h2[6] = fmaf(rin, wb.z, h2[6]);
            h2[7] = fmaf(rin, wb.w, h2[7]);
        }
    }

    float4 o0 = {h2[0], h2[1], h2[2], h2[3]};
    float4 o1 = {h2[4], h2[5], h2[6], h2[7]};
    *(float4*)&hout[(size_t)(n0 + nl) * D + dg * 8]     = o0;
    *(float4*)&hout[(size_t)(n0 + nl) * D + dg * 8 + 4] = o1;
}

// ---------------------------------------------------------------- edge out (MFMA)
__global__ __launch_bounds__(256) void edge_out_mfma(
    const int* __restrict__ edge, const float* __restrict__ r,
    const float* __restrict__ W_erp, const float* __restrict__ b_erp,
    const float* __restrict__ h, float* __restrict__ t)
{
    __shared__ unsigned short P[EB2][64];
    __shared__ int ij_s[EB2][2];

    const int tid = threadIdx.x;
    const int w  = tid >> 6;
    const int l  = tid & 63;
    const int lr = l & 15;
    const int lg = l >> 4;

    bf16x8 wf[8][2];
    float bias[8];
#pragma unroll
    for (int dt = 0; dt < 8; ++dt) {
        const int col = dt * 16 + lr;
        bias[dt] = b_erp[col];
#pragma unroll
        for (int s = 0; s < 2; ++s) {
            bf16x8 v;
#pragma unroll
            for (int j = 0; j < 8; ++j) {
                const int k = s * 32 + lg * 8 + j;
                v[j] = (k < NRBF) ? (short)f2bf(W_erp[k * D + col]) : (short)0;
            }
            wf[dt][s] = v;
        }
    }

    const float start = expf(-RCUT);
    const float step  = (1.0f - start) / (NRBF - 1);
    const float bq    = (2.0f / NRBF) * (1.0f - start);
    const float beta  = 1.0f / (bq * bq);

    const int prow  = tid & 63;
    const int kbase = (tid >> 6) * 16;

    const int nbatch = NE / EB2;
    for (int batch = blockIdx.x; batch < nbatch; batch += gridDim.x) {
        const int eb = batch * EB2;
        if (tid < EB2) {
            const int2 ep = ((const int2*)edge)[eb + tid];
            ij_s[tid][0] = ep.x;
            ij_s[tid][1] = ep.y;
        }
        {
            const float er = __expf(-r[eb + prow]);
#pragma unroll
            for (int kk = 0; kk < 16; kk += 2) {
                const int k0 = kbase + kk;
                unsigned int pk = 0;
#pragma unroll
                for (int c = 0; c < 2; ++c) {
                    const int k = k0 + c;
                    float v = 0.0f;
                    if (k < NRBF) {
                        const float diff = er - (start + (float)k * step);
                        v = __expf(-beta * diff * diff);
                    }
                    pk |= ((unsigned int)f2bf(v)) << (16 * c);
                }
                const int swc = (k0 >> 3) ^ (prow & 7);
                *(unsigned int*)&P[prow][swc * 8 + (k0 & 7)] = pk;
            }
        }
        __syncthreads();

        const int arow = w * 16 + lr;
        bf16x8 af[2];
#pragma unroll
        for (int s = 0; s < 2; ++s) {
            const int swc = (s * 4 + lg) ^ (arow & 7);
            af[s] = *(const bf16x8*)&P[arow][swc * 8];
        }
        int vi[4], vj[4];
#pragma unroll
        for (int q = 0; q < 4; ++q) {
            const int erow = w * 16 + lg * 4 + q;
            vi[q] = ij_s[erow][0];
            vj[q] = ij_s[erow][1];
        }
#pragma unroll
        for (int dt = 0; dt < 8; ++dt) {
            f32x4 acc = {0.0f, 0.0f, 0.0f, 0.0f};
            acc = __builtin_amdgcn_mfma_f32_16x16x32_bf16(af[0], wf[dt][0], acc, 0, 0, 0);
            acc = __builtin_amdgcn_mfma_f32_16x16x32_bf16(af[1], wf[dt][1], acc, 0, 0, 0);
            const int col = dt * 16 + lr;
#pragma unroll
            for (int q = 0; q < 4; ++q) {
                const int e = eb + w * 16 + lg * 4 + q;
                const float hv = h[(size_t)vi[q] * D + col] + h[(size_t)vj[q] * D + col];
                t[(size_t)e * D + col] = hv * (acc[q] + bias[dt]);
            }
        }
        __syncthreads();
    }
}

// ---------------------------------------------------------------- launch
extern "C" void kernel_launch(void* const* d_in, const int* in_sizes, int n_in,
                              void* d_out, int out_size, void* d_ws, size_t ws_size,
                              hipStream_t stream) {
    const float* z      = (const float*)d_in[0];
    const int*   edge   = (const int*)d_in[1];
    const float* r      = (const float*)d_in[2];
    const float* u      = (const float*)d_in[3];
    const float* A_na_w  = (const float*)d_in[4];
    const float* A_na_b  = (const float*)d_in[5];
    const float* A_nbr_w = (const float*)d_in[6];
    const float* A_nbr_b = (const float*)d_in[7];
    const float* W_ndp_w = (const float*)d_in[8];
    const float* W_ndp_b = (const float*)d_in[9];
    const float* W_nrd_w = (const float*)d_in[10];
    const float* W_nrd_b = (const float*)d_in[11];
    const float* W_nru_w = (const float*)d_in[12];
    const float* W_nru_b = (const float*)d_in[13];
    const float* W_erp_w = (const float*)d_in[14];
    const float* W_erp_b = (const float*)d_in[15];
    const float* ln_g    = (const float*)d_in[16];
    const float* ln_b    = (const float*)d_in[17];

    float* out = (float*)d_out;
    float* h_out   = out;
    float* t_out   = out + (size_t)NN * D;
    float* rt0_out = t_out + (size_t)NE * D;
    float* rt1_out = rt0_out + (size_t)NE;
    float* rt2_out = rt1_out + (size_t)NE * 3;
    float* c_out   = rt2_out + (size_t)NE * 5;

    float* nbr_ws = (float*)d_ws;
    float* m_ws   = nbr_ws + (size_t)NN * D;

    int* elist  = (int*)t_out;           // NE
    int* off    = elist + NE;            // NN+1
    int* cursor = off + (NN + 1);        // NN
    int* bsum   = cursor + NN;           // 256

    hipMemsetAsync(cursor, 0, (size_t)NN * sizeof(int), stream);

    nbr_kernel<<<NN, 128, 0, stream>>>(z, A_nbr_w, A_nbr_b, nbr_ws);

    aux_kernel<<<(NE + 255) / 256, 256, 0, stream>>>(
        edge, r, u, rt0_out, rt1_out, rt2_out, c_out, cursor);

    scan1_kernel<<<SCAN_B, 256, 0, stream>>>(cursor, off, bsum);
    scan2_kernel<<<1, 256, 0, stream>>>(bsum);
    scan3_kernel<<<SCAN_B, 256, 0, stream>>>(off, bsum);

    hipMemsetAsync(cursor, 0, (size_t)NN * sizeof(int), stream);

    scatter_kernel<<<(NE + 255) / 256, 256, 0, stream>>>(edge, off, cursor, elist);

    gather_msg_mfma<<<NN, 128, 0, stream>>>(
        elist, off, edge, r, W_ndp_w, W_ndp_b, nbr_ws, m_ws);

    node_kernel2<<<NN / NB, 256, 0, stream>>>(
        z, A_na_w, A_na_b, m_ws, W_nrd_w, W_nrd_b,
        W_nru_w, W_nru_b, ln_g, ln_b, h_out);

    edge_out_mfma<<<EDGE_GRID, 256, 0, stream>>>(
        edge, r, W_erp_w, W_erp_b, h_out, t_out);
}

// Round 5
// 850.090 us; speedup vs baseline: 2.1559x; 1.4376x over previous
//
#include <hip/hip_runtime.h>
#include <hip/hip_bf16.h>
#include <math.h>

#define NN 50000
#define NE 1600000
#define D 128
#define NRBF 50
#define RCUT 5.0f
#define LNEPS 1e-5f
#define EB 16
#define EB2 64
#define EDGE_GRID 2048
#define SCAN_B 196   // ceil(50000/256)
#define NB 16
#define NPB 8        // nodes per block in gather

typedef __attribute__((ext_vector_type(8))) short bf16x8;
typedef __attribute__((ext_vector_type(4))) float f32x4;

__device__ __forceinline__ float silu_f(float x) {
    return x / (1.0f + __expf(-x));
}
__device__ __forceinline__ unsigned short f2bf(float x) {
    __hip_bfloat16 b = __float2bfloat16(x);
    return *reinterpret_cast<unsigned short*>(&b);
}
__device__ __forceinline__ float bf2f(unsigned short u) {
    unsigned int x = ((unsigned int)u) << 16;
    return __uint_as_float(x);
}

// ---------------------------------------------------------------- kernel 1
// nbr_bf = bf16(silu(z @ A_nbr_w + A_nbr_b))
__global__ __launch_bounds__(128) void nbr_kernel(
    const float* __restrict__ z, const float* __restrict__ Aw,
    const float* __restrict__ Ab, unsigned short* __restrict__ nbr_bf)
{
    const int n = blockIdx.x;
    const int d = threadIdx.x;
    float acc = Ab[d];
#pragma unroll
    for (int k = 0; k < 25; ++k)
        acc = fmaf(z[n * 25 + k], Aw[k * D + d], acc);
    nbr_bf[(size_t)n * D + d] = f2bf(silu_f(acc));
}

// ---------------------------------------------------------------- kernel 2
__global__ __launch_bounds__(256) void aux_kernel(
    const int* __restrict__ edge, const float* __restrict__ r,
    const float* __restrict__ u, float* __restrict__ rt0,
    float* __restrict__ rt1, float* __restrict__ rt2,
    float* __restrict__ cout, int* __restrict__ cnt)
{
    const int e = blockIdx.x * 256 + threadIdx.x;
    if (e >= NE) return;
    const float rr = r[e];
    rt0[e] = rr;
    const float cc = (rr < RCUT)
        ? 0.5f * (__cosf(3.14159265358979f * rr * (1.0f / RCUT)) + 1.0f)
        : 0.0f;
    cout[e] = cc;
    const float x  = u[e * 3 + 0];
    const float y  = u[e * 3 + 1];
    const float zc = u[e * 3 + 2];
    rt1[(size_t)e * 3 + 0] = x;
    rt1[(size_t)e * 3 + 1] = y;
    rt1[(size_t)e * 3 + 2] = zc;
    const float s3 = 1.7320508075688772f;
    rt2[(size_t)e * 5 + 0] = s3 * x * y;
    rt2[(size_t)e * 5 + 1] = s3 * y * zc;
    rt2[(size_t)e * 5 + 2] = 0.5f * (3.0f * zc * zc - 1.0f);
    rt2[(size_t)e * 5 + 3] = s3 * zc * x;
    rt2[(size_t)e * 5 + 4] = 0.5f * s3 * (x * x - y * y);
    atomicAdd(&cnt[edge[2 * e]], 1);
}

// ---------------------------------------------------------------- scans
__global__ __launch_bounds__(256) void scan1_kernel(
    const int* __restrict__ cnt, int* __restrict__ off, int* __restrict__ bsum)
{
    __shared__ int s[2][256];
    const int t = threadIdx.x;
    const int g = blockIdx.x * 256 + t;
    const int v = (g < NN) ? cnt[g] : 0;
    int incl = v;
    s[0][t] = incl;
    __syncthreads();
    int cur = 0;
#pragma unroll
    for (int dd = 1; dd < 256; dd <<= 1) {
        const int add = (t >= dd) ? s[cur][t - dd] : 0;
        incl += add;
        s[cur ^ 1][t] = incl;
        __syncthreads();
        cur ^= 1;
    }
    if (g < NN) off[g] = incl - v;
    if (t == 255) bsum[blockIdx.x] = incl;
}

__global__ __launch_bounds__(256) void scan2_kernel(int* __restrict__ bsum)
{
    __shared__ int s[2][256];
    const int t = threadIdx.x;
    const int v = (t < SCAN_B) ? bsum[t] : 0;
    int incl = v;
    s[0][t] = incl;
    __syncthreads();
    int cur = 0;
#pragma unroll
    for (int dd = 1; dd < 256; dd <<= 1) {
        const int add = (t >= dd) ? s[cur][t - dd] : 0;
        incl += add;
        s[cur ^ 1][t] = incl;
        __syncthreads();
        cur ^= 1;
    }
    if (t < SCAN_B) bsum[t] = incl - v;
}

__global__ __launch_bounds__(256) void scan3_kernel(
    int* __restrict__ off, const int* __restrict__ bsum)
{
    const int g = blockIdx.x * 256 + threadIdx.x;
    if (g < NN) off[g] += bsum[blockIdx.x];
    if (g == 0) off[NN] = NE;
}

// ---------------------------------------------------------------- scatter
__global__ __launch_bounds__(256) void scatter_kernel(
    const int* __restrict__ edge, const int* __restrict__ off,
    int* __restrict__ cursor, int* __restrict__ elist)
{
    const int e = blockIdx.x * 256 + threadIdx.x;
    if (e >= NE) return;
    const int i = edge[2 * e];
    const int pos = atomicAdd(&cursor[i], 1);
    elist[off[i] + pos] = e;
}

// ---------------------------------------------------------------- gather msg (MFMA, bf16 nbr, 8 nodes/block)
__global__ __launch_bounds__(128) void gather_msg_mfma(
    const int* __restrict__ elist, const int* __restrict__ off,
    const int* __restrict__ edge, const float* __restrict__ r,
    const float* __restrict__ W_ndp, const float* __restrict__ b_ndp,
    const unsigned short* __restrict__ nbr_bf, float* __restrict__ m)
{
    __shared__ unsigned short P[EB][64];
    __shared__ float er_s[EB];
    __shared__ float c_s[EB];
    __shared__ int   j_s[EB];

    const int tid = threadIdx.x;
    const int w   = tid >> 6;
    const int l   = tid & 63;
    const int lr  = l & 15;
    const int lg  = l >> 4;

    bf16x8 wf[4][2];
#pragma unroll
    for (int dt = 0; dt < 4; ++dt) {
        const int col = w * 64 + dt * 16 + lr;
#pragma unroll
        for (int s = 0; s < 2; ++s) {
            bf16x8 v;
#pragma unroll
            for (int j = 0; j < 8; ++j) {
                const int k = s * 32 + lg * 8 + j;
                float wv = 0.0f;
                if (k < NRBF)       wv = W_ndp[k * D + col];
                else if (k == NRBF) wv = b_ndp[col];
                v[j] = (short)f2bf(wv);
            }
            wf[dt][s] = v;
        }
    }

    const float start = expf(-RCUT);
    const float step  = (1.0f - start) / (NRBF - 1);
    const float bq    = (2.0f / NRBF) * (1.0f - start);
    const float beta  = 1.0f / (bq * bq);

    const int prow = tid >> 3;
    const int pci  = tid & 7;

    for (int nn = 0; nn < NPB; ++nn) {
        const int n   = blockIdx.x * NPB + nn;
        const int s0  = off[n];
        const int deg = off[n + 1] - s0;

        f32x4 macc[4] = {{0,0,0,0},{0,0,0,0},{0,0,0,0},{0,0,0,0}};

        for (int base = 0; base < deg; base += EB) {
            const int chunk = min(EB, deg - base);
            if (tid < EB) {
                if (tid < chunk) {
                    const int eid = elist[s0 + base + tid];
                    const float rr = r[eid];
                    er_s[tid] = __expf(-rr);
                    c_s[tid] = (rr < RCUT)
                        ? 0.5f * (__cosf(3.14159265358979f * rr * (1.0f / RCUT)) + 1.0f)
                        : 0.0f;
                    j_s[tid] = edge[2 * eid + 1];
                } else {
                    er_s[tid] = 0.0f; c_s[tid] = 0.0f; j_s[tid] = 0;
                }
            }
            __syncthreads();
            {
                const float er = er_s[prow];
                const float cc = c_s[prow];
                unsigned int pk[4];
#pragma unroll
                for (int p2 = 0; p2 < 4; ++p2) {
                    unsigned int word = 0;
#pragma unroll
                    for (int c = 0; c < 2; ++c) {
                        const int k = pci * 8 + p2 * 2 + c;
                        float v = 0.0f;
                        if (k < NRBF) {
                            const float diff = er - (start + (float)k * step);
                            v = cc * __expf(-beta * diff * diff);
                        } else if (k == NRBF) {
                            v = cc;
                        }
                        word |= ((unsigned int)f2bf(v)) << (16 * c);
                    }
                    pk[p2] = word;
                }
                const int swc = pci ^ (prow & 7);
                *(uint4*)&P[prow][swc * 8] = make_uint4(pk[0], pk[1], pk[2], pk[3]);
            }
            __syncthreads();
            bf16x8 af[2];
#pragma unroll
            for (int s = 0; s < 2; ++s) {
                const int swc = (s * 4 + lg) ^ (lr & 7);
                af[s] = *(const bf16x8*)&P[lr][swc * 8];
            }
            int jrow[4];
#pragma unroll
            for (int q = 0; q < 4; ++q) jrow[q] = j_s[lg * 4 + q];
#pragma unroll
            for (int dt = 0; dt < 4; ++dt) {
                f32x4 acc = {0.0f, 0.0f, 0.0f, 0.0f};
                acc = __builtin_amdgcn_mfma_f32_16x16x32_bf16(af[0], wf[dt][0], acc, 0, 0, 0);
                acc = __builtin_amdgcn_mfma_f32_16x16x32_bf16(af[1], wf[dt][1], acc, 0, 0, 0);
                const int col = w * 64 + dt * 16 + lr;
#pragma unroll
                for (int q = 0; q < 4; ++q) {
                    const float nv = bf2f(nbr_bf[(size_t)jrow[q] * D + col]);
                    macc[dt][q] = fmaf(nv, acc[q], macc[dt][q]);
                }
            }
            __syncthreads();
        }

#pragma unroll
        for (int dt = 0; dt < 4; ++dt) {
            float v = macc[dt][0] + macc[dt][1] + macc[dt][2] + macc[dt][3];
            v += __shfl_xor(v, 16);
            v += __shfl_xor(v, 32);
            if (lg == 0)
                m[(size_t)n * D + w * 64 + dt * 16 + lr] = v;
        }
    }
}

// ---------------------------------------------------------------- node MLP
__global__ __launch_bounds__(256) void node_kernel2(
    const float* __restrict__ z, const float* __restrict__ A_na_w,
    const float* __restrict__ A_na_b, const float* __restrict__ m,
    const float* __restrict__ W_nrd_w, const float* __restrict__ W_nrd_b,
    const float* __restrict__ W_nru_w, const float* __restrict__ W_nru_b,
    const float* __restrict__ ln_g, const float* __restrict__ ln_b,
    float* __restrict__ hout, unsigned short* __restrict__ h_bf)
{
    __shared__ float inbuf[NB][260];
    __shared__ float wbuf[32][128];
    __shared__ float part[4][NB][2];

    const int tid = threadIdx.x;
    const int n0 = blockIdx.x * NB;
    const int nl = tid & 15;
    const int dg = tid >> 4;

    for (int idx = tid; idx < NB * 128; idx += 256) {
        const int n = idx >> 7;
        const int d = idx & 127;
        float acc = A_na_b[d];
#pragma unroll
        for (int k = 0; k < 25; ++k)
            acc = fmaf(z[(size_t)(n0 + n) * 25 + k], A_na_w[k * D + d], acc);
        inbuf[n][d]       = silu_f(acc);
        inbuf[n][128 + d] = m[(size_t)(n0 + n) * D + d];
    }

    float h1[8];
#pragma unroll
    for (int dd = 0; dd < 8; ++dd) h1[dd] = W_nrd_b[dg * 8 + dd];

    for (int tile = 0; tile < 8; ++tile) {
        __syncthreads();
        for (int v = tid; v < 32 * 32; v += 256) {
            const int row = v >> 5;
            const int c4  = (v & 31) * 4;
            *(float4*)&wbuf[row][c4] =
                *(const float4*)&W_nrd_w[(size_t)(tile * 32 + row) * D + c4];
        }
        __syncthreads();
#pragma unroll 4
        for (int k = 0; k < 32; ++k) {
            const float rin = inbuf[nl][tile * 32 + k];
            const float4 wa = *(const float4*)&wbuf[k][dg * 8];
            const float4 wb = *(const float4*)&wbuf[k][dg * 8 + 4];
            h1[0] = fmaf(rin, wa.x, h1[0]);
            h1[1] = fmaf(rin, wa.y, h1[1]);
            h1[2] = fmaf(rin, wa.z, h1[2]);
            h1[3] = fmaf(rin, wa.w, h1[3]);
            h1[4] = fmaf(rin, wb.x, h1[4]);
            h1[5] = fmaf(rin, wb.y, h1[5]);
            h1[6] = fmaf(rin, wb.z, h1[6]);
            h1[7] = fmaf(rin, wb.w, h1[7]);
        }
    }

    float s = 0.0f, sq = 0.0f;
#pragma unroll
    for (int dd = 0; dd < 8; ++dd) { s += h1[dd]; sq += h1[dd] * h1[dd]; }
    s  += __shfl_xor(s, 16);  sq += __shfl_xor(sq, 16);
    s  += __shfl_xor(s, 32);  sq += __shfl_xor(sq, 32);
    const int wv = tid >> 6;
    if ((tid & 63) < 16) { part[wv][nl][0] = s; part[wv][nl][1] = sq; }
    __syncthreads();
    float ts = 0.0f, tsq = 0.0f;
#pragma unroll
    for (int w = 0; w < 4; ++w) { ts += part[w][nl][0]; tsq += part[w][nl][1]; }
    const float mu  = ts * (1.0f / 128.0f);
    const float var = tsq * (1.0f / 128.0f) - mu * mu;
    const float inv = rsqrtf(var + LNEPS);

#pragma unroll
    for (int dd = 0; dd < 8; ++dd) {
        const int d = dg * 8 + dd;
        inbuf[nl][d] = silu_f((h1[dd] - mu) * inv * ln_g[d] + ln_b[d]);
    }

    float h2[8];
#pragma unroll
    for (int dd = 0; dd < 8; ++dd) h2[dd] = W_nru_b[dg * 8 + dd];

    for (int tile = 0; tile < 4; ++tile) {
        __syncthreads();
        for (int v = tid; v < 32 * 32; v += 256) {
            const int row = v >> 5;
            const int c4  = (v & 31) * 4;
            *(float4*)&wbuf[row][c4] =
                *(const float4*)&W_nru_w[(size_t)(tile * 32 + row) * D + c4];
        }
        __syncthreads();
#pragma unroll 4
        for (int k = 0; k < 32; ++k) {
            const float rin = inbuf[nl][tile * 32 + k];
            const float4 wa = *(const float4*)&wbuf[k][dg * 8];
            const float4 wb = *(const float4*)&wbuf[k][dg * 8 + 4];
            h2[0] = fmaf(rin, wa.x, h2[0]);
            h2[1] = fmaf(rin, wa.y, h2[1]);
            h2[2] = fmaf(rin, wa.z, h2[2]);
            h2[3] = fmaf(rin, wa.w, h2[3]);
            h2[4] = fmaf(rin, wb.x, h2[4]);
            h2[5] = fmaf(rin, wb.y, h2[5]);
            h2[6] = fmaf(rin, wb.z, h2[6]);
            h2[7] = fmaf(rin, wb.w, h2[7]);
        }
    }

    float4 o0 = {h2[0], h2[1], h2[2], h2[3]};
    float4 o1 = {h2[4], h2[5], h2[6], h2[7]};
    *(float4*)&hout[(size_t)(n0 + nl) * D + dg * 8]     = o0;
    *(float4*)&hout[(size_t)(n0 + nl) * D + dg * 8 + 4] = o1;

    unsigned int b0 = (unsigned int)f2bf(h2[0]) | ((unsigned int)f2bf(h2[1]) << 16);
    unsigned int b1 = (unsigned int)f2bf(h2[2]) | ((unsigned int)f2bf(h2[3]) << 16);
    unsigned int b2 = (unsigned int)f2bf(h2[4]) | ((unsigned int)f2bf(h2[5]) << 16);
    unsigned int b3 = (unsigned int)f2bf(h2[6]) | ((unsigned int)f2bf(h2[7]) << 16);
    *(uint4*)&h_bf[(size_t)(n0 + nl) * D + dg * 8] = make_uint4(b0, b1, b2, b3);
}

// ---------------------------------------------------------------- edge out (MFMA, bf16 h, LDS hv staging)
__global__ __launch_bounds__(256) void edge_out_mfma(
    const int* __restrict__ edge, const float* __restrict__ r,
    const float* __restrict__ W_erp, const float* __restrict__ b_erp,
    const unsigned short* __restrict__ h_bf, float* __restrict__ t)
{
    __shared__ unsigned short P[EB2][64];       // 8 KB
    __shared__ unsigned short hv[EB2][136];     // 17.4 KB (pad 8 halfs)
    __shared__ int ij_s[EB2][2];

    const int tid = threadIdx.x;
    const int w  = tid >> 6;
    const int l  = tid & 63;
    const int lr = l & 15;
    const int lg = l >> 4;

    bf16x8 wf[8][2];
    float bias[8];
#pragma unroll
    for (int dt = 0; dt < 8; ++dt) {
        const int col = dt * 16 + lr;
        bias[dt] = b_erp[col];
#pragma unroll
        for (int s = 0; s < 2; ++s) {
            bf16x8 v;
#pragma unroll
            for (int j = 0; j < 8; ++j) {
                const int k = s * 32 + lg * 8 + j;
                v[j] = (k < NRBF) ? (short)f2bf(W_erp[k * D + col]) : (short)0;
            }
            wf[dt][s] = v;
        }
    }

    const float start = expf(-RCUT);
    const float step  = (1.0f - start) / (NRBF - 1);
    const float bq    = (2.0f / NRBF) * (1.0f - start);
    const float beta  = 1.0f / (bq * bq);

    const int prow  = tid & 63;
    const int kbase = (tid >> 6) * 16;

    const int nbatch = NE / EB2;
    for (int batch = blockIdx.x; batch < nbatch; batch += gridDim.x) {
        const int eb = batch * EB2;
        if (tid < EB2) {
            const int2 ep = ((const int2*)edge)[eb + tid];
            ij_s[tid][0] = ep.x;
            ij_s[tid][1] = ep.y;
        }
        {
            const float er = __expf(-r[eb + prow]);
            const int kc0 = kbase >> 3;
#pragma unroll
            for (int c2 = 0; c2 < 2; ++c2) {
                const int kc = kc0 + c2;
                unsigned int pk[4];
#pragma unroll
                for (int p2 = 0; p2 < 4; ++p2) {
                    unsigned int word = 0;
#pragma unroll
                    for (int c = 0; c < 2; ++c) {
                        const int k = kc * 8 + p2 * 2 + c;
                        float v = 0.0f;
                        if (k < NRBF) {
                            const float diff = er - (start + (float)k * step);
                            v = __expf(-beta * diff * diff);
                        }
                        word |= ((unsigned int)f2bf(v)) << (16 * c);
                    }
                    pk[p2] = word;
                }
                const int swc = kc ^ (prow & 7);
                *(uint4*)&P[prow][swc * 8] = make_uint4(pk[0], pk[1], pk[2], pk[3]);
            }
        }
        __syncthreads();

        // A fragments (P ready)
        const int arow = w * 16 + lr;
        bf16x8 af[2];
#pragma unroll
        for (int s = 0; s < 2; ++s) {
            const int swc = (s * 4 + lg) ^ (arow & 7);
            af[s] = *(const bf16x8*)&P[arow][swc * 8];
        }

        // stage hv rows: hv[el][:] = bf16(h[i]+h[j]) (coalesced uint4 loads)
#pragma unroll
        for (int idx = tid; idx < EB2 * 16; idx += 256) {
            const int el = idx >> 4;
            const int ch = idx & 15;
            const uint4 ui = *((const uint4*)(h_bf + (size_t)ij_s[el][0] * D) + ch);
            const uint4 uj = *((const uint4*)(h_bf + (size_t)ij_s[el][1] * D) + ch);
            const unsigned int wi[4] = {ui.x, ui.y, ui.z, ui.w};
            const unsigned int wj[4] = {uj.x, uj.y, uj.z, uj.w};
            unsigned int wo[4];
#pragma unroll
            for (int p = 0; p < 4; ++p) {
                const float lo = bf2f((unsigned short)(wi[p] & 0xffff))
                               + bf2f((unsigned short)(wj[p] & 0xffff));
                const float hi = bf2f((unsigned short)(wi[p] >> 16))
                               + bf2f((unsigned short)(wj[p] >> 16));
                wo[p] = (unsigned int)f2bf(lo) | ((unsigned int)f2bf(hi) << 16);
            }
            *(uint4*)&hv[el][ch * 8] = make_uint4(wo[0], wo[1], wo[2], wo[3]);
        }
        __syncthreads();

#pragma unroll
        for (int dt = 0; dt < 8; ++dt) {
            f32x4 acc = {0.0f, 0.0f, 0.0f, 0.0f};
            acc = __builtin_amdgcn_mfma_f32_16x16x32_bf16(af[0], wf[dt][0], acc, 0, 0, 0);
            acc = __builtin_amdgcn_mfma_f32_16x16x32_bf16(af[1], wf[dt][1], acc, 0, 0, 0);
            const int col = dt * 16 + lr;
#pragma unroll
            for (int q = 0; q < 4; ++q) {
                const int el = w * 16 + lg * 4 + q;
                const float hvf = bf2f(hv[el][col]);
                t[(size_t)(eb + el) * D + col] = hvf * (acc[q] + bias[dt]);
            }
        }
        __syncthreads();
    }
}

// ---------------------------------------------------------------- launch
extern "C" void kernel_launch(void* const* d_in, const int* in_sizes, int n_in,
                              void* d_out, int out_size, void* d_ws, size_t ws_size,
                              hipStream_t stream) {
    const float* z      = (const float*)d_in[0];
    const int*   edge   = (const int*)d_in[1];
    const float* r      = (const float*)d_in[2];
    const float* u      = (const float*)d_in[3];
    const float* A_na_w  = (const float*)d_in[4];
    const float* A_na_b  = (const float*)d_in[5];
    const float* A_nbr_w = (const float*)d_in[6];
    const float* A_nbr_b = (const float*)d_in[7];
    const float* W_ndp_w = (const float*)d_in[8];
    const float* W_ndp_b = (const float*)d_in[9];
    const float* W_nrd_w = (const float*)d_in[10];
    const float* W_nrd_b = (const float*)d_in[11];
    const float* W_nru_w = (const float*)d_in[12];
    const float* W_nru_b = (const float*)d_in[13];
    const float* W_erp_w = (const float*)d_in[14];
    const float* W_erp_b = (const float*)d_in[15];
    const float* ln_g    = (const float*)d_in[16];
    const float* ln_b    = (const float*)d_in[17];

    float* out = (float*)d_out;
    float* h_out   = out;
    float* t_out   = out + (size_t)NN * D;
    float* rt0_out = t_out + (size_t)NE * D;
    float* rt1_out = rt0_out + (size_t)NE;
    float* rt2_out = rt1_out + (size_t)NE * 3;
    float* c_out   = rt2_out + (size_t)NE * 5;

    // ws: nbr_bf (12.8MB) | m f32 (25.6MB) | h_bf (12.8MB)
    unsigned short* nbr_bf = (unsigned short*)d_ws;
    float* m_ws   = (float*)((char*)d_ws + (size_t)NN * D * sizeof(unsigned short));
    unsigned short* h_bf = (unsigned short*)((char*)m_ws + (size_t)NN * D * sizeof(float));

    int* elist  = (int*)t_out;           // NE
    int* off    = elist + NE;            // NN+1
    int* cursor = off + (NN + 1);        // NN
    int* bsum   = cursor + NN;           // 256

    hipMemsetAsync(cursor, 0, (size_t)NN * sizeof(int), stream);

    nbr_kernel<<<NN, 128, 0, stream>>>(z, A_nbr_w, A_nbr_b, nbr_bf);

    aux_kernel<<<(NE + 255) / 256, 256, 0, stream>>>(
        edge, r, u, rt0_out, rt1_out, rt2_out, c_out, cursor);

    scan1_kernel<<<SCAN_B, 256, 0, stream>>>(cursor, off, bsum);
    scan2_kernel<<<1, 256, 0, stream>>>(bsum);
    scan3_kernel<<<SCAN_B, 256, 0, stream>>>(off, bsum);

    hipMemsetAsync(cursor, 0, (size_t)NN * sizeof(int), stream);

    scatter_kernel<<<(NE + 255) / 256, 256, 0, stream>>>(edge, off, cursor, elist);

    gather_msg_mfma<<<NN / NPB, 128, 0, stream>>>(
        elist, off, edge, r, W_ndp_w, W_ndp_b, nbr_bf, m_ws);

    node_kernel2<<<NN / NB, 256, 0, stream>>>(
        z, A_na_w, A_na_b, m_ws, W_nrd_w, W_nrd_b,
        W_nru_w, W_nru_b, ln_g, ln_b, h_out, h_bf);

    edge_out_mfma<<<EDGE_GRID, 256, 0, stream>>>(
        edge, r, W_erp_w, W_erp_b, h_bf, t_out);
}

// Round 6
// 845.994 us; speedup vs baseline: 2.1664x; 1.0048x over previous
//
#include <hip/hip_runtime.h>
#include <hip/hip_bf16.h>
#include <math.h>

#define NN 50000
#define NE 1600000
#define D 128
#define NRBF 50
#define RCUT 5.0f
#define LNEPS 1e-5f
#define EB 16
#define EB2 64
#define EDGE_GRID 2048
#define SCAN_B 196   // ceil(50000/256)
#define NB 16
#define NPB 8        // nodes per block in gather

typedef __attribute__((ext_vector_type(8))) short bf16x8;
typedef __attribute__((ext_vector_type(4))) float f32x4;

__device__ __forceinline__ float silu_f(float x) {
    return x / (1.0f + __expf(-x));
}
__device__ __forceinline__ unsigned short f2bf(float x) {
    __hip_bfloat16 b = __float2bfloat16(x);
    return *reinterpret_cast<unsigned short*>(&b);
}
__device__ __forceinline__ float bf2f(unsigned short u) {
    unsigned int x = ((unsigned int)u) << 16;
    return __uint_as_float(x);
}

// ---------------------------------------------------------------- kernel 1
__global__ __launch_bounds__(128) void nbr_kernel(
    const float* __restrict__ z, const float* __restrict__ Aw,
    const float* __restrict__ Ab, unsigned short* __restrict__ nbr_bf)
{
    const int n = blockIdx.x;
    const int d = threadIdx.x;
    float acc = Ab[d];
#pragma unroll
    for (int k = 0; k < 25; ++k)
        acc = fmaf(z[n * 25 + k], Aw[k * D + d], acc);
    nbr_bf[(size_t)n * D + d] = f2bf(silu_f(acc));
}

// ---------------------------------------------------------------- kernel 2
__global__ __launch_bounds__(256) void aux_kernel(
    const int* __restrict__ edge, const float* __restrict__ r,
    const float* __restrict__ u, float* __restrict__ rt0,
    float* __restrict__ rt1, float* __restrict__ rt2,
    float* __restrict__ cout, int* __restrict__ cnt)
{
    const int e = blockIdx.x * 256 + threadIdx.x;
    if (e >= NE) return;
    const float rr = r[e];
    rt0[e] = rr;
    const float cc = (rr < RCUT)
        ? 0.5f * (__cosf(3.14159265358979f * rr * (1.0f / RCUT)) + 1.0f)
        : 0.0f;
    cout[e] = cc;
    const float x  = u[e * 3 + 0];
    const float y  = u[e * 3 + 1];
    const float zc = u[e * 3 + 2];
    rt1[(size_t)e * 3 + 0] = x;
    rt1[(size_t)e * 3 + 1] = y;
    rt1[(size_t)e * 3 + 2] = zc;
    const float s3 = 1.7320508075688772f;
    rt2[(size_t)e * 5 + 0] = s3 * x * y;
    rt2[(size_t)e * 5 + 1] = s3 * y * zc;
    rt2[(size_t)e * 5 + 2] = 0.5f * (3.0f * zc * zc - 1.0f);
    rt2[(size_t)e * 5 + 3] = s3 * zc * x;
    rt2[(size_t)e * 5 + 4] = 0.5f * s3 * (x * x - y * y);
    atomicAdd(&cnt[edge[2 * e]], 1);
}

// ---------------------------------------------------------------- scans
__global__ __launch_bounds__(256) void scan1_kernel(
    const int* __restrict__ cnt, int* __restrict__ off, int* __restrict__ bsum)
{
    __shared__ int s[2][256];
    const int t = threadIdx.x;
    const int g = blockIdx.x * 256 + t;
    const int v = (g < NN) ? cnt[g] : 0;
    int incl = v;
    s[0][t] = incl;
    __syncthreads();
    int cur = 0;
#pragma unroll
    for (int dd = 1; dd < 256; dd <<= 1) {
        const int add = (t >= dd) ? s[cur][t - dd] : 0;
        incl += add;
        s[cur ^ 1][t] = incl;
        __syncthreads();
        cur ^= 1;
    }
    if (g < NN) off[g] = incl - v;
    if (t == 255) bsum[blockIdx.x] = incl;
}

__global__ __launch_bounds__(256) void scan2_kernel(int* __restrict__ bsum)
{
    __shared__ int s[2][256];
    const int t = threadIdx.x;
    const int v = (t < SCAN_B) ? bsum[t] : 0;
    int incl = v;
    s[0][t] = incl;
    __syncthreads();
    int cur = 0;
#pragma unroll
    for (int dd = 1; dd < 256; dd <<= 1) {
        const int add = (t >= dd) ? s[cur][t - dd] : 0;
        incl += add;
        s[cur ^ 1][t] = incl;
        __syncthreads();
        cur ^= 1;
    }
    if (t < SCAN_B) bsum[t] = incl - v;
}

__global__ __launch_bounds__(256) void scan3_kernel(
    int* __restrict__ off, const int* __restrict__ bsum)
{
    const int g = blockIdx.x * 256 + threadIdx.x;
    if (g < NN) off[g] += bsum[blockIdx.x];
    if (g == 0) off[NN] = NE;
}

// ---------------------------------------------------------------- scatter
// writes packed {j, r_bits} per CSR slot -> gather reads are contiguous
__global__ __launch_bounds__(256) void scatter_kernel(
    const int* __restrict__ edge, const float* __restrict__ r,
    const int* __restrict__ off, int* __restrict__ cursor,
    uint2* __restrict__ jr)
{
    const int e = blockIdx.x * 256 + threadIdx.x;
    if (e >= NE) return;
    const int2 ep = ((const int2*)edge)[e];
    const int pos = atomicAdd(&cursor[ep.x], 1);
    uint2 v;
    v.x = (unsigned int)ep.y;
    v.y = __float_as_uint(r[e]);
    jr[off[ep.x] + pos] = v;
}

// ---------------------------------------------------------------- gather msg (MFMA)
// col permutation: col = w*64 + lr*4 + dt  (dt 0..3) -> nbr gather is one
// 8B load per q; m write is one float4 per lane.
__global__ __launch_bounds__(128) void gather_msg_mfma(
    const uint2* __restrict__ jr, const int* __restrict__ off,
    const float* __restrict__ W_ndp, const float* __restrict__ b_ndp,
    const unsigned short* __restrict__ nbr_bf, float* __restrict__ m)
{
    __shared__ unsigned short P[EB][64];
    __shared__ float er_s[EB];
    __shared__ float c_s[EB];
    __shared__ int   j_s[EB];

    const int tid = threadIdx.x;
    const int w   = tid >> 6;
    const int l   = tid & 63;
    const int lr  = l & 15;
    const int lg  = l >> 4;

    // B fragments with permuted col map
    bf16x8 wf[4][2];
#pragma unroll
    for (int dt = 0; dt < 4; ++dt) {
        const int col = w * 64 + lr * 4 + dt;
#pragma unroll
        for (int s = 0; s < 2; ++s) {
            bf16x8 v;
#pragma unroll
            for (int j = 0; j < 8; ++j) {
                const int k = s * 32 + lg * 8 + j;
                float wv = 0.0f;
                if (k < NRBF)       wv = W_ndp[k * D + col];
                else if (k == NRBF) wv = b_ndp[col];
                v[j] = (short)f2bf(wv);
            }
            wf[dt][s] = v;
        }
    }

    const float start = expf(-RCUT);
    const float step  = (1.0f - start) / (NRBF - 1);
    const float bq    = (2.0f / NRBF) * (1.0f - start);
    const float beta  = 1.0f / (bq * bq);

    const int prow = tid >> 3;
    const int pci  = tid & 7;

    for (int nn = 0; nn < NPB; ++nn) {
        const int n   = blockIdx.x * NPB + nn;
        const int s0  = off[n];
        const int deg = off[n + 1] - s0;

        f32x4 macc[4] = {{0,0,0,0},{0,0,0,0},{0,0,0,0},{0,0,0,0}};

        for (int base = 0; base < deg; base += EB) {
            const int chunk = min(EB, deg - base);
            if (tid < EB) {
                if (tid < chunk) {
                    const uint2 v = jr[s0 + base + tid];   // contiguous!
                    const float rr = __uint_as_float(v.y);
                    er_s[tid] = __expf(-rr);
                    c_s[tid] = (rr < RCUT)
                        ? 0.5f * (__cosf(3.14159265358979f * rr * (1.0f / RCUT)) + 1.0f)
                        : 0.0f;
                    j_s[tid] = (int)v.x;
                } else {
                    er_s[tid] = 0.0f; c_s[tid] = 0.0f; j_s[tid] = 0;
                }
            }
            __syncthreads();
            {
                const float er = er_s[prow];
                const float cc = c_s[prow];
                unsigned int pk[4];
#pragma unroll
                for (int p2 = 0; p2 < 4; ++p2) {
                    unsigned int word = 0;
#pragma unroll
                    for (int c = 0; c < 2; ++c) {
                        const int k = pci * 8 + p2 * 2 + c;
                        float v = 0.0f;
                        if (k < NRBF) {
                            const float diff = er - (start + (float)k * step);
                            v = cc * __expf(-beta * diff * diff);
                        } else if (k == NRBF) {
                            v = cc;
                        }
                        word |= ((unsigned int)f2bf(v)) << (16 * c);
                    }
                    pk[p2] = word;
                }
                const int swc = pci ^ (prow & 7);
                *(uint4*)&P[prow][swc * 8] = make_uint4(pk[0], pk[1], pk[2], pk[3]);
            }
            __syncthreads();
            bf16x8 af[2];
#pragma unroll
            for (int s = 0; s < 2; ++s) {
                const int swc = (s * 4 + lg) ^ (lr & 7);
                af[s] = *(const bf16x8*)&P[lr][swc * 8];
            }
            // all 4 MFMAs first (accs), then one 8B nbr load per q
            f32x4 accs[4];
#pragma unroll
            for (int dt = 0; dt < 4; ++dt) {
                f32x4 acc = {0.0f, 0.0f, 0.0f, 0.0f};
                acc = __builtin_amdgcn_mfma_f32_16x16x32_bf16(af[0], wf[dt][0], acc, 0, 0, 0);
                acc = __builtin_amdgcn_mfma_f32_16x16x32_bf16(af[1], wf[dt][1], acc, 0, 0, 0);
                accs[dt] = acc;
            }
#pragma unroll
            for (int q = 0; q < 4; ++q) {
                const int row = j_s[lg * 4 + q];
                const uint2 nv8 = *(const uint2*)(nbr_bf + (size_t)row * D + w * 64 + lr * 4);
                const float n0 = bf2f((unsigned short)(nv8.x & 0xffff));
                const float n1 = bf2f((unsigned short)(nv8.x >> 16));
                const float n2 = bf2f((unsigned short)(nv8.y & 0xffff));
                const float n3 = bf2f((unsigned short)(nv8.y >> 16));
                macc[0][q] = fmaf(n0, accs[0][q], macc[0][q]);
                macc[1][q] = fmaf(n1, accs[1][q], macc[1][q]);
                macc[2][q] = fmaf(n2, accs[2][q], macc[2][q]);
                macc[3][q] = fmaf(n3, accs[3][q], macc[3][q]);
            }
            __syncthreads();
        }

        float v0 = macc[0][0] + macc[0][1] + macc[0][2] + macc[0][3];
        float v1 = macc[1][0] + macc[1][1] + macc[1][2] + macc[1][3];
        float v2 = macc[2][0] + macc[2][1] + macc[2][2] + macc[2][3];
        float v3 = macc[3][0] + macc[3][1] + macc[3][2] + macc[3][3];
        v0 += __shfl_xor(v0, 16); v0 += __shfl_xor(v0, 32);
        v1 += __shfl_xor(v1, 16); v1 += __shfl_xor(v1, 32);
        v2 += __shfl_xor(v2, 16); v2 += __shfl_xor(v2, 32);
        v3 += __shfl_xor(v3, 16); v3 += __shfl_xor(v3, 32);
        if (lg == 0) {
            float4 o = {v0, v1, v2, v3};
            *(float4*)&m[(size_t)n * D + w * 64 + lr * 4] = o;
        }
    }
}

// ---------------------------------------------------------------- node MLP
__global__ __launch_bounds__(256) void node_kernel2(
    const float* __restrict__ z, const float* __restrict__ A_na_w,
    const float* __restrict__ A_na_b, const float* __restrict__ m,
    const float* __restrict__ W_nrd_w, const float* __restrict__ W_nrd_b,
    const float* __restrict__ W_nru_w, const float* __restrict__ W_nru_b,
    const float* __restrict__ ln_g, const float* __restrict__ ln_b,
    float* __restrict__ hout, unsigned short* __restrict__ h_bf)
{
    __shared__ float inbuf[NB][260];
    __shared__ float wbuf[32][128];
    __shared__ float part[4][NB][2];

    const int tid = threadIdx.x;
    const int n0 = blockIdx.x * NB;
    const int nl = tid & 15;
    const int dg = tid >> 4;

    for (int idx = tid; idx < NB * 128; idx += 256) {
        const int n = idx >> 7;
        const int d = idx & 127;
        float acc = A_na_b[d];
#pragma unroll
        for (int k = 0; k < 25; ++k)
            acc = fmaf(z[(size_t)(n0 + n) * 25 + k], A_na_w[k * D + d], acc);
        inbuf[n][d]       = silu_f(acc);
        inbuf[n][128 + d] = m[(size_t)(n0 + n) * D + d];
    }

    float h1[8];
#pragma unroll
    for (int dd = 0; dd < 8; ++dd) h1[dd] = W_nrd_b[dg * 8 + dd];

    for (int tile = 0; tile < 8; ++tile) {
        __syncthreads();
        for (int v = tid; v < 32 * 32; v += 256) {
            const int row = v >> 5;
            const int c4  = (v & 31) * 4;
            *(float4*)&wbuf[row][c4] =
                *(const float4*)&W_nrd_w[(size_t)(tile * 32 + row) * D + c4];
        }
        __syncthreads();
#pragma unroll 4
        for (int k = 0; k < 32; ++k) {
            const float rin = inbuf[nl][tile * 32 + k];
            const float4 wa = *(const float4*)&wbuf[k][dg * 8];
            const float4 wb = *(const float4*)&wbuf[k][dg * 8 + 4];
            h1[0] = fmaf(rin, wa.x, h1[0]);
            h1[1] = fmaf(rin, wa.y, h1[1]);
            h1[2] = fmaf(rin, wa.z, h1[2]);
            h1[3] = fmaf(rin, wa.w, h1[3]);
            h1[4] = fmaf(rin, wb.x, h1[4]);
            h1[5] = fmaf(rin, wb.y, h1[5]);
            h1[6] = fmaf(rin, wb.z, h1[6]);
            h1[7] = fmaf(rin, wb.w, h1[7]);
        }
    }

    float s = 0.0f, sq = 0.0f;
#pragma unroll
    for (int dd = 0; dd < 8; ++dd) { s += h1[dd]; sq += h1[dd] * h1[dd]; }
    s  += __shfl_xor(s, 16);  sq += __shfl_xor(sq, 16);
    s  += __shfl_xor(s, 32);  sq += __shfl_xor(sq, 32);
    const int wv = tid >> 6;
    if ((tid & 63) < 16) { part[wv][nl][0] = s; part[wv][nl][1] = sq; }
    __syncthreads();
    float ts = 0.0f, tsq = 0.0f;
#pragma unroll
    for (int w = 0; w < 4; ++w) { ts += part[w][nl][0]; tsq += part[w][nl][1]; }
    const float mu  = ts * (1.0f / 128.0f);
    const float var = tsq * (1.0f / 128.0f) - mu * mu;
    const float inv = rsqrtf(var + LNEPS);

#pragma unroll
    for (int dd = 0; dd < 8; ++dd) {
        const int d = dg * 8 + dd;
        inbuf[nl][d] = silu_f((h1[dd] - mu) * inv * ln_g[d] + ln_b[d]);
    }

    float h2[8];
#pragma unroll
    for (int dd = 0; dd < 8; ++dd) h2[dd] = W_nru_b[dg * 8 + dd];

    for (int tile = 0; tile < 4; ++tile) {
        __syncthreads();
        for (int v = tid; v < 32 * 32; v += 256) {
            const int row = v >> 5;
            const int c4  = (v & 31) * 4;
            *(float4*)&wbuf[row][c4] =
                *(const float4*)&W_nru_w[(size_t)(tile * 32 + row) * D + c4];
        }
        __syncthreads();
#pragma unroll 4
        for (int k = 0; k < 32; ++k) {
            const float rin = inbuf[nl][tile * 32 + k];
            const float4 wa = *(const float4*)&wbuf[k][dg * 8];
            const float4 wb = *(const float4*)&wbuf[k][dg * 8 + 4];
            h2[0] = fmaf(rin, wa.x, h2[0]);
            h2[1] = fmaf(rin, wa.y, h2[1]);
            h2[2] = fmaf(rin, wa.z, h2[2]);
            h2[3] = fmaf(rin, wa.w, h2[3]);
            h2[4] = fmaf(rin, wb.x, h2[4]);
            h2[5] = fmaf(rin, wb.y, h2[5]);
            h2[6] = fmaf(rin, wb.z, h2[6]);
            h2[7] = fmaf(rin, wb.w, h2[7]);
        }
    }

    float4 o0 = {h2[0], h2[1], h2[2], h2[3]};
    float4 o1 = {h2[4], h2[5], h2[6], h2[7]};
    *(float4*)&hout[(size_t)(n0 + nl) * D + dg * 8]     = o0;
    *(float4*)&hout[(size_t)(n0 + nl) * D + dg * 8 + 4] = o1;

    unsigned int b0 = (unsigned int)f2bf(h2[0]) | ((unsigned int)f2bf(h2[1]) << 16);
    unsigned int b1 = (unsigned int)f2bf(h2[2]) | ((unsigned int)f2bf(h2[3]) << 16);
    unsigned int b2 = (unsigned int)f2bf(h2[4]) | ((unsigned int)f2bf(h2[5]) << 16);
    unsigned int b3 = (unsigned int)f2bf(h2[6]) | ((unsigned int)f2bf(h2[7]) << 16);
    *(uint4*)&h_bf[(size_t)(n0 + nl) * D + dg * 8] = make_uint4(b0, b1, b2, b3);
}

// ---------------------------------------------------------------- edge out (MFMA)
// col permutation: col = lr*8 + dt (dt 0..7) -> hv read is one bf16x8 LDS
// read; t write is two float4s per q (full row coalescing).
__global__ __launch_bounds__(256) void edge_out_mfma(
    const int* __restrict__ edge, const float* __restrict__ r,
    const float* __restrict__ W_erp, const float* __restrict__ b_erp,
    const unsigned short* __restrict__ h_bf, float* __restrict__ t)
{
    __shared__ unsigned short P[EB2][64];       // 8 KB
    __shared__ unsigned short hv[EB2][136];     // 17.4 KB
    __shared__ int ij_s[EB2][2];

    const int tid = threadIdx.x;
    const int w  = tid >> 6;
    const int l  = tid & 63;
    const int lr = l & 15;
    const int lg = l >> 4;

    bf16x8 wf[8][2];
    float bias[8];
#pragma unroll
    for (int dt = 0; dt < 8; ++dt) {
        const int col = lr * 8 + dt;
        bias[dt] = b_erp[col];
#pragma unroll
        for (int s = 0; s < 2; ++s) {
            bf16x8 v;
#pragma unroll
            for (int j = 0; j < 8; ++j) {
                const int k = s * 32 + lg * 8 + j;
                v[j] = (k < NRBF) ? (short)f2bf(W_erp[k * D + col]) : (short)0;
            }
            wf[dt][s] = v;
        }
    }

    const float start = expf(-RCUT);
    const float step  = (1.0f - start) / (NRBF - 1);
    const float bq    = (2.0f / NRBF) * (1.0f - start);
    const float beta  = 1.0f / (bq * bq);

    const int prow  = tid & 63;
    const int kbase = (tid >> 6) * 16;

    const int nbatch = NE / EB2;
    for (int batch = blockIdx.x; batch < nbatch; batch += gridDim.x) {
        const int eb = batch * EB2;
        if (tid < EB2) {
            const int2 ep = ((const int2*)edge)[eb + tid];
            ij_s[tid][0] = ep.x;
            ij_s[tid][1] = ep.y;
        }
        {
            const float er = __expf(-r[eb + prow]);
            const int kc0 = kbase >> 3;
#pragma unroll
            for (int c2 = 0; c2 < 2; ++c2) {
                const int kc = kc0 + c2;
                unsigned int pk[4];
#pragma unroll
                for (int p2 = 0; p2 < 4; ++p2) {
                    unsigned int word = 0;
#pragma unroll
                    for (int c = 0; c < 2; ++c) {
                        const int k = kc * 8 + p2 * 2 + c;
                        float v = 0.0f;
                        if (k < NRBF) {
                            const float diff = er - (start + (float)k * step);
                            v = __expf(-beta * diff * diff);
                        }
                        word |= ((unsigned int)f2bf(v)) << (16 * c);
                    }
                    pk[p2] = word;
                }
                const int swc = kc ^ (prow & 7);
                *(uint4*)&P[prow][swc * 8] = make_uint4(pk[0], pk[1], pk[2], pk[3]);
            }
        }
        __syncthreads();

        const int arow = w * 16 + lr;
        bf16x8 af[2];
#pragma unroll
        for (int s = 0; s < 2; ++s) {
            const int swc = (s * 4 + lg) ^ (arow & 7);
            af[s] = *(const bf16x8*)&P[arow][swc * 8];
        }

        // stage hv rows (coalesced uint4 loads of both endpoint rows)
#pragma unroll
        for (int idx = tid; idx < EB2 * 16; idx += 256) {
            const int el = idx >> 4;
            const int ch = idx & 15;
            const uint4 ui = *((const uint4*)(h_bf + (size_t)ij_s[el][0] * D) + ch);
            const uint4 uj = *((const uint4*)(h_bf + (size_t)ij_s[el][1] * D) + ch);
            const unsigned int wi[4] = {ui.x, ui.y, ui.z, ui.w};
            const unsigned int wj[4] = {uj.x, uj.y, uj.z, uj.w};
            unsigned int wo[4];
#pragma unroll
            for (int p = 0; p < 4; ++p) {
                const float lo = bf2f((unsigned short)(wi[p] & 0xffff))
                               + bf2f((unsigned short)(wj[p] & 0xffff));
                const float hi = bf2f((unsigned short)(wi[p] >> 16))
                               + bf2f((unsigned short)(wj[p] >> 16));
                wo[p] = (unsigned int)f2bf(lo) | ((unsigned int)f2bf(hi) << 16);
            }
            *(uint4*)&hv[el][ch * 8] = make_uint4(wo[0], wo[1], wo[2], wo[3]);
        }
        __syncthreads();

        f32x4 accs[8];
#pragma unroll
        for (int dt = 0; dt < 8; ++dt) {
            f32x4 acc = {0.0f, 0.0f, 0.0f, 0.0f};
            acc = __builtin_amdgcn_mfma_f32_16x16x32_bf16(af[0], wf[dt][0], acc, 0, 0, 0);
            acc = __builtin_amdgcn_mfma_f32_16x16x32_bf16(af[1], wf[dt][1], acc, 0, 0, 0);
            accs[dt] = acc;
        }
#pragma unroll
        for (int q = 0; q < 4; ++q) {
            const int el = w * 16 + lg * 4 + q;
            const bf16x8 hv8 = *(const bf16x8*)&hv[el][lr * 8];
            float o[8];
#pragma unroll
            for (int dt = 0; dt < 8; ++dt)
                o[dt] = bf2f((unsigned short)hv8[dt]) * (accs[dt][q] + bias[dt]);
            float4 o0 = {o[0], o[1], o[2], o[3]};
            float4 o1 = {o[4], o[5], o[6], o[7]};
            float* tp = &t[(size_t)(eb + el) * D + lr * 8];
            *(float4*)tp       = o0;
            *(float4*)(tp + 4) = o1;
        }
        __syncthreads();
    }
}

// ---------------------------------------------------------------- launch
extern "C" void kernel_launch(void* const* d_in, const int* in_sizes, int n_in,
                              void* d_out, int out_size, void* d_ws, size_t ws_size,
                              hipStream_t stream) {
    const float* z      = (const float*)d_in[0];
    const int*   edge   = (const int*)d_in[1];
    const float* r      = (const float*)d_in[2];
    const float* u      = (const float*)d_in[3];
    const float* A_na_w  = (const float*)d_in[4];
    const float* A_na_b  = (const float*)d_in[5];
    const float* A_nbr_w = (const float*)d_in[6];
    const float* A_nbr_b = (const float*)d_in[7];
    const float* W_ndp_w = (const float*)d_in[8];
    const float* W_ndp_b = (const float*)d_in[9];
    const float* W_nrd_w = (const float*)d_in[10];
    const float* W_nrd_b = (const float*)d_in[11];
    const float* W_nru_w = (const float*)d_in[12];
    const float* W_nru_b = (const float*)d_in[13];
    const float* W_erp_w = (const float*)d_in[14];
    const float* W_erp_b = (const float*)d_in[15];
    const float* ln_g    = (const float*)d_in[16];
    const float* ln_b    = (const float*)d_in[17];

    float* out = (float*)d_out;
    float* h_out   = out;
    float* t_out   = out + (size_t)NN * D;
    float* rt0_out = t_out + (size_t)NE * D;
    float* rt1_out = rt0_out + (size_t)NE;
    float* rt2_out = rt1_out + (size_t)NE * 3;
    float* c_out   = rt2_out + (size_t)NE * 5;

    // ws: nbr_bf (12.8MB) | m f32 (25.6MB) | h_bf (12.8MB)
    unsigned short* nbr_bf = (unsigned short*)d_ws;
    float* m_ws   = (float*)((char*)d_ws + (size_t)NN * D * sizeof(unsigned short));
    unsigned short* h_bf = (unsigned short*)((char*)m_ws + (size_t)NN * D * sizeof(float));

    // CSR scratch in the (written-last) t region of d_out
    uint2* jr   = (uint2*)t_out;                 // NE uint2 (12.8 MB)
    int* off    = (int*)(jr + NE);               // NN+1
    int* cursor = off + (NN + 1);                // NN
    int* bsum   = cursor + NN;                   // 256

    hipMemsetAsync(cursor, 0, (size_t)NN * sizeof(int), stream);

    nbr_kernel<<<NN, 128, 0, stream>>>(z, A_nbr_w, A_nbr_b, nbr_bf);

    aux_kernel<<<(NE + 255) / 256, 256, 0, stream>>>(
        edge, r, u, rt0_out, rt1_out, rt2_out, c_out, cursor);

    scan1_kernel<<<SCAN_B, 256, 0, stream>>>(cursor, off, bsum);
    scan2_kernel<<<1, 256, 0, stream>>>(bsum);
    scan3_kernel<<<SCAN_B, 256, 0, stream>>>(off, bsum);

    hipMemsetAsync(cursor, 0, (size_t)NN * sizeof(int), stream);

    scatter_kernel<<<(NE + 255) / 256, 256, 0, stream>>>(edge, r, off, cursor, jr);

    gather_msg_mfma<<<NN / NPB, 128, 0, stream>>>(
        jr, off, W_ndp_w, W_ndp_b, nbr_bf, m_ws);

    node_kernel2<<<NN / NB, 256, 0, stream>>>(
        z, A_na_w, A_na_b, m_ws, W_nrd_w, W_nrd_b,
        W_nru_w, W_nru_b, ln_g, ln_b, h_out, h_bf);

    edge_out_mfma<<<EDGE_GRID, 256, 0, stream>>>(
        edge, r, W_erp_w, W_erp_b, h_bf, t_out);
}